// Round 2
// baseline (7325.691 us; speedup 1.0000x reference)
//
#include <hip/hip_runtime.h>
#include <math.h>

// ---------------- problem constants ----------------
constexpr int CB=2048, CMA=6, CS=11, CSP=10, CD=256, CH=4, CDH=64, CL=12;
constexpr int CNREL=500, CNTYPE=1000, CNODE=100000, CVOC=99000, CNCLS=1500;
constexpr int NN  = CB*CMA;     // 12288 GAT nodes
constexpr int NSR = CB*CS;      // 22528 sequence rows
constexpr int NTAB= 3+CNTYPE;   // 1003 distinct type-embedding rows
constexpr float BIGF = 1000000.0f;

__device__ __forceinline__ float lreluf(float x){ return x>=0.f ? x : 0.2f*x; }
__device__ __forceinline__ float eluf1(float x){ return x>0.f ? x : expm1f(x); }
__device__ __forceinline__ float geluf(float x){ return 0.5f*x*(1.f+erff(x*0.70710678118654752f)); }

// block=256 reductions (4 waves)
__device__ __forceinline__ float blk_sum(float v, float* red){
#pragma unroll
  for (int o=32;o;o>>=1) v += __shfl_down(v,o,64);
  __syncthreads();
  if ((threadIdx.x&63)==0) red[threadIdx.x>>6]=v;
  __syncthreads();
  return red[0]+red[1]+red[2]+red[3];
}
__device__ __forceinline__ float blk_max(float v, float* red){
#pragma unroll
  for (int o=32;o;o>>=1) v = fmaxf(v,__shfl_down(v,o,64));
  __syncthreads();
  if ((threadIdx.x&63)==0) red[threadIdx.x>>6]=v;
  __syncthreads();
  return fmaxf(fmaxf(red[0],red[1]),fmaxf(red[2],red[3]));
}

// ---------------- type prep: itt[n][sp] ----------------
__global__ __launch_bounds__(256)
void k_typeprep(const int* __restrict__ input_ids, const int* __restrict__ ent_types,
                int* __restrict__ itt)
{
  int idx = blockIdx.x*256 + threadIdx.x;
  if (idx >= NN*CSP) return;
  int n = idx / CSP, sp = idx % CSP;
  int b = n / CMA, ma = n % CMA;
  int id = input_ids[b*CS + 2*ma] - CNREL;            // in [0, 3+E)
  itt[idx] = (id < 3) ? id : ent_types[(size_t)(id-3)*(CSP+1) + sp + 1];
}

// ---------------- distinct-row table: TW = T@W, Ts=TW@a_src, Tt=TW@a_dst ----------------
__global__ __launch_bounds__(256)
void k_tables(const float* __restrict__ emb, const float* __restrict__ W,
              const float* __restrict__ asrc, const float* __restrict__ adst,
              float* __restrict__ TW, float* __restrict__ Ts, float* __restrict__ Tt)
{
  __shared__ float row[CD];
  __shared__ float red[8];
  const int r = blockIdx.x, d = threadIdx.x;
  const int nrow = (r<3) ? r : (CVOC + (r-3));
  row[d] = emb[(size_t)nrow*CD + d];
  __syncthreads();
  float acc = 0.f;
  for (int k=0;k<CD;k+=4){
    const float4 hv = *reinterpret_cast<const float4*>(&row[k]);
    acc = fmaf(hv.x, W[(size_t)(k+0)*CD+d],
          fmaf(hv.y, W[(size_t)(k+1)*CD+d],
          fmaf(hv.z, W[(size_t)(k+2)*CD+d],
          fmaf(hv.w, W[(size_t)(k+3)*CD+d], acc))));
  }
  TW[(size_t)r*CD+d] = acc;
  float s = blk_sum(acc*asrc[d], red);
  float t = blk_sum(acc*adst[d], red);
  if (d==0){ Ts[r]=s; Tt[r]=t; }
}

// ---------------- g1 reductions for GAT2 layer-1 gather (GW = g1@W computed by k_gemm128) --
__global__ __launch_bounds__(256)
void k_g1red(const float* __restrict__ g1, const float* __restrict__ GW,
             const float* __restrict__ asrc, const float* __restrict__ adst,
             float* __restrict__ Gs, float* __restrict__ Gt, float* __restrict__ Grs)
{
  __shared__ float red[8];
  const int n = blockIdx.x, d = threadIdx.x;
  float w = GW[(size_t)n*CD + d];
  float v = g1[(size_t)n*CD + d];
  float s  = blk_sum(w*asrc[d], red);
  float t  = blk_sum(w*adst[d], red);
  float rs = blk_sum(v, red);
  if (d==0){ Gs[n]=s; Gt[n]=t; Grs[n]=rs; }
}

// ---------------- GAT masked softmax (thread i owns row i) ----------------
template<int P>
__device__ __forceinline__ void gat_softmax(float (*att)[P+1], const float* sA,
                                            const float* tA, const int* sg)
{
  const int i = threadIdx.x;
  if (i < P){
    if (sg[i]){
      float si = sA[i];
      float e[P];
      float m = -3.0e38f;
#pragma unroll
      for (int j=0;j<P;j++){
        e[j] = 0.f;
        if (sg[j]){ e[j] = lreluf(si + tA[j]); m = fmaxf(m, e[j]); }
      }
      float s = 0.f;
#pragma unroll
      for (int j=0;j<P;j++){
        float w = sg[j] ? expf(e[j]-m) : 0.f;   // masked j: exactly 0 (matches exp(-1e6) underflow)
        att[i][j] = w; s += w;
      }
      float inv = 1.f/s;
#pragma unroll
      for (int j=0;j<P;j++) att[i][j] *= inv;
    } else {
#pragma unroll
      for (int j=0;j<P;j++) att[i][j] = 0.f;
    }
  }
}

// ---------------- fused per-node 2-layer GAT (128 threads, 2 cols/thread) ----------------
template<int P>
__global__ __launch_bounds__(128)
void k_gat(const int* __restrict__ itt,
           const float* __restrict__ TW, const float* __restrict__ Ts, const float* __restrict__ Tt,
           const float* __restrict__ GW, const float* __restrict__ Gs, const float* __restrict__ Gt,
           const float* __restrict__ Grs, const int* __restrict__ l2m,
           const float* __restrict__ W2, const float* __restrict__ as2, const float* __restrict__ ad2,
           float* __restrict__ gout)
{
  __shared__ float hW[P][CD];
  __shared__ float att[P][P+1];
  __shared__ float sA[P], tA[P];
  __shared__ int   sg[P], ridx[P];
  const int n = blockIdx.x;
  const int t = threadIdx.x;          // 0..127
  const int d0 = t, d1 = t + 128;

  if (t < P){
    if (t < CSP){
      int it = itt[n*CSP + t];
      int r = (it < 3) ? it : (it - (CVOC - 3));
      ridx[t]=r; sg[t]=(it>0); sA[t]=Ts[r]; tA[t]=Tt[r];
    } else {
      int ma = n % CMA;
      int m = l2m[ma*(CMA-1) + (t - CSP)];
      int nb = (n / CMA)*CMA + m;
      ridx[t]=nb; sg[t]=(Grs[nb]!=0.f); sA[t]=Gs[nb]; tA[t]=Gt[nb];
    }
  }
  __syncthreads();
#pragma unroll
  for (int i=0;i<P;i++){
    const float* src = (i<CSP) ? TW : GW;
    const float* r = src + (size_t)ridx[i]*CD;
    hW[i][d0] = r[d0]; hW[i][d1] = r[d1];
  }
  __syncthreads();
  gat_softmax<P>(att, sA, tA, sg);
  __syncthreads();
  // h = elu(att @ hW) kept in registers, then written back into hW
  {
    float h0[P], h1[P];
#pragma unroll
    for (int i=0;i<P;i++){ h0[i]=0.f; h1[i]=0.f; }
#pragma unroll
    for (int j=0;j<P;j++){
      float w0 = hW[j][d0], w1 = hW[j][d1];
#pragma unroll
      for (int i=0;i<P;i++){
        float a = att[i][j];
        h0[i] = fmaf(a, w0, h0[i]);
        h1[i] = fmaf(a, w1, h1[i]);
      }
    }
    __syncthreads();
#pragma unroll
    for (int i=0;i<P;i++){ hW[i][d0] = eluf1(h0[i]); hW[i][d1] = eluf1(h1[i]); }
  }
  __syncthreads();
  // layer-2 GEMM: acc[i] = h[i] @ W2 for columns d0,d1 (hW reads are wave broadcasts)
  float a0[P], a1[P];
#pragma unroll
  for (int i=0;i<P;i++){ a0[i]=0.f; a1[i]=0.f; }
  for (int k=0;k<CD;k+=4){
    float q00=W2[(size_t)(k+0)*CD+d0], q01=W2[(size_t)(k+1)*CD+d0];
    float q02=W2[(size_t)(k+2)*CD+d0], q03=W2[(size_t)(k+3)*CD+d0];
    float q10=W2[(size_t)(k+0)*CD+d1], q11=W2[(size_t)(k+1)*CD+d1];
    float q12=W2[(size_t)(k+2)*CD+d1], q13=W2[(size_t)(k+3)*CD+d1];
#pragma unroll
    for (int i=0;i<P;i++){
      const float4 hv = *reinterpret_cast<const float4*>(&hW[i][k]);
      a0[i] = fmaf(hv.x,q00,fmaf(hv.y,q01,fmaf(hv.z,q02,fmaf(hv.w,q03,a0[i]))));
      a1[i] = fmaf(hv.x,q10,fmaf(hv.y,q11,fmaf(hv.z,q12,fmaf(hv.w,q13,a1[i]))));
    }
  }
  __syncthreads();
#pragma unroll
  for (int i=0;i<P;i++){ hW[i][d0] = a0[i]; hW[i][d1] = a1[i]; }
  __syncthreads();
  // s2/t2: 8 lanes per row i
  {
    int i = t>>3, l = t&7;
    if (i < P){
      float ps=0.f, pt=0.f;
      for (int d=l; d<CD; d+=8){
        float w = hW[i][d];
        ps = fmaf(w, as2[d], ps);
        pt = fmaf(w, ad2[d], pt);
      }
#pragma unroll
      for (int o=4;o;o>>=1){ ps += __shfl_down(ps,o,8); pt += __shfl_down(pt,o,8); }
      if (l==0){ sA[i]=ps; tA[i]=pt; }
    }
  }
  __syncthreads();
  gat_softmax<P>(att, sA, tA, sg);
  __syncthreads();
  float den = 0.f;
#pragma unroll
  for (int i=0;i<P;i++) den += (float)sg[i];
  den = fmaxf(den, 1.f);
  float x0[P], x1[P];
#pragma unroll
  for (int i=0;i<P;i++){ x0[i]=0.f; x1[i]=0.f; }
#pragma unroll
  for (int j=0;j<P;j++){
    float w0 = hW[j][d0], w1 = hW[j][d1];
#pragma unroll
    for (int i=0;i<P;i++){
      float a = att[i][j];
      x0[i] = fmaf(a, w0, x0[i]);
      x1[i] = fmaf(a, w1, x1[i]);
    }
  }
  float o0=0.f, o1=0.f;
#pragma unroll
  for (int i=0;i<P;i++){
    if (sg[i]){ o0 += eluf1(x0[i]); o1 += eluf1(x1[i]); }
  }
  gout[(size_t)n*CD + d0] = o0/den;
  gout[(size_t)n*CD + d1] = o1/den;
}

// ---------------- build x0 = emb_out after g2 & mask-row substitution ----------------
__global__ __launch_bounds__(256)
void k_x0(const int* __restrict__ input_ids, const int* __restrict__ mask_pos,
          const int* __restrict__ mask_type, const float* __restrict__ emb,
          const float* __restrict__ g2, const float* __restrict__ g,
          const float* __restrict__ bta, float* __restrict__ x)
{
  __shared__ float red[8];
  const int row = blockIdx.x;
  const int b = row / CS, s = row % CS;
  const int d = threadIdx.x;
  float* xrow = x + (size_t)row*CD;
  if (s == mask_pos[b]){
    int mm = (mask_type[b]==1) ? 2 : 1;
    xrow[d] = emb[(size_t)mm*CD + d];
  } else if ((s & 1) == 0){
    xrow[d] = g2[(size_t)(b*CMA + (s>>1))*CD + d];
  } else {
    float v = emb[(size_t)input_ids[row]*CD + d];
    float m = blk_sum(v, red)*(1.f/CD);
    float dv = v - m;
    float var = blk_sum(dv*dv, red)*(1.f/CD);
    xrow[d] = dv/sqrtf(var+1e-12f)*g[d] + bta[d];
  }
}

// ---------------- 128x128-tile f32 GEMM: C = act(A@B + bias) ----------------
// A: MxK row-major, B: KxN row-major. M%128==0, N%128==0, K%16==0.
template<int ACT, bool BIAS>
__global__ __launch_bounds__(256)
void k_gemm128(const float* __restrict__ A, const float* __restrict__ Bm,
               const float* __restrict__ bias, float* __restrict__ C,
               int M, int N, int K)
{
  __shared__ alignas(16) float As[16][132];
  __shared__ alignas(16) float Bs[16][132];
  const int tid = threadIdx.x;
  const int bn = blockIdx.x*128, bm = blockIdx.y*128;
  const int tx = tid & 15, ty = tid >> 4;
  const int ar = tid >> 1, ak = (tid & 1)*8;   // A loader
  const int bk = tid >> 4, bnl = (tid & 15)*8; // B loader
  const float* Ap = A + (size_t)(bm + ar)*K + ak;
  const float* Bp = Bm + (size_t)bk*N + bn + bnl;
  float acc[8][8] = {};
  for (int k0=0; k0<K; k0+=16){
    float4 av0 = *reinterpret_cast<const float4*>(Ap + k0);
    float4 av1 = *reinterpret_cast<const float4*>(Ap + k0 + 4);
    float4 bv0 = *reinterpret_cast<const float4*>(Bp + (size_t)k0*N);
    float4 bv1 = *reinterpret_cast<const float4*>(Bp + (size_t)k0*N + 4);
    __syncthreads();
    As[ak+0][ar]=av0.x; As[ak+1][ar]=av0.y; As[ak+2][ar]=av0.z; As[ak+3][ar]=av0.w;
    As[ak+4][ar]=av1.x; As[ak+5][ar]=av1.y; As[ak+6][ar]=av1.z; As[ak+7][ar]=av1.w;
    *reinterpret_cast<float4*>(&Bs[bk][bnl])   = bv0;
    *reinterpret_cast<float4*>(&Bs[bk][bnl+4]) = bv1;
    __syncthreads();
#pragma unroll
    for (int kk=0; kk<16; kk++){
      float a_[8], b_[8];
      *reinterpret_cast<float4*>(&a_[0]) = *reinterpret_cast<const float4*>(&As[kk][ty*8]);
      *reinterpret_cast<float4*>(&a_[4]) = *reinterpret_cast<const float4*>(&As[kk][ty*8+4]);
      *reinterpret_cast<float4*>(&b_[0]) = *reinterpret_cast<const float4*>(&Bs[kk][tx*8]);
      *reinterpret_cast<float4*>(&b_[4]) = *reinterpret_cast<const float4*>(&Bs[kk][tx*8+4]);
#pragma unroll
      for (int i=0;i<8;i++)
#pragma unroll
        for (int j=0;j<8;j++) acc[i][j] = fmaf(a_[i], b_[j], acc[i][j]);
    }
  }
#pragma unroll
  for (int i=0;i<8;i++){
    const int row = bm + ty*8 + i;
    float outv[8];
#pragma unroll
    for (int j=0;j<8;j++){
      float v = acc[i][j];
      if (BIAS) v += bias[bn + tx*8 + j];
      if (ACT==1) v = geluf(v);
      outv[j] = v;
    }
    *reinterpret_cast<float4*>(C + (size_t)row*N + bn + tx*8)     = *reinterpret_cast<float4*>(&outv[0]);
    *reinterpret_cast<float4*>(C + (size_t)row*N + bn + tx*8 + 4) = *reinterpret_cast<float4*>(&outv[4]);
  }
}

// ---------------- 64x256-tile f32 GEMM with fused residual + LayerNorm epilogue ----------
// C = LN(A@B (+bias) + res). N fixed at 256 (full row per block). In-place C==res is safe.
template<bool BIAS>
__global__ __launch_bounds__(256)
void k_gemm64ln(const float* __restrict__ A, const float* __restrict__ Bm,
                const float* __restrict__ bias, const float* __restrict__ res,
                const float* __restrict__ lng, const float* __restrict__ lnb,
                float* __restrict__ C, int M, int K)
{
  constexpr int N = 256;
  __shared__ alignas(16) float As[16][68];
  __shared__ alignas(16) float Bs[16][260];
  const int tid = threadIdx.x;
  const int bm = blockIdx.x*64;
  const int tx = tid & 31, ty = tid >> 5;   // 32 x 8 thread grid
  const int ar = tid >> 2, ak = (tid & 3)*4;   // A loader
  const int bk = tid >> 4, bnl = (tid & 15)*16;// B loader
  const float* Ap = A + (size_t)(bm + ar)*K + ak;
  const float* Bp = Bm + (size_t)bk*N + bnl;
  float acc[8][8] = {};
  for (int k0=0; k0<K; k0+=16){
    float4 a0 = *reinterpret_cast<const float4*>(Ap + k0);
    float4 b0 = *reinterpret_cast<const float4*>(Bp + (size_t)k0*N);
    float4 b1 = *reinterpret_cast<const float4*>(Bp + (size_t)k0*N + 4);
    float4 b2 = *reinterpret_cast<const float4*>(Bp + (size_t)k0*N + 8);
    float4 b3 = *reinterpret_cast<const float4*>(Bp + (size_t)k0*N + 12);
    __syncthreads();
    As[ak+0][ar]=a0.x; As[ak+1][ar]=a0.y; As[ak+2][ar]=a0.z; As[ak+3][ar]=a0.w;
    *reinterpret_cast<float4*>(&Bs[bk][bnl])    = b0;
    *reinterpret_cast<float4*>(&Bs[bk][bnl+4])  = b1;
    *reinterpret_cast<float4*>(&Bs[bk][bnl+8])  = b2;
    *reinterpret_cast<float4*>(&Bs[bk][bnl+12]) = b3;
    __syncthreads();
#pragma unroll
    for (int kk=0; kk<16; kk++){
      float a_[8], b_[8];
      *reinterpret_cast<float4*>(&a_[0]) = *reinterpret_cast<const float4*>(&As[kk][ty*8]);
      *reinterpret_cast<float4*>(&a_[4]) = *reinterpret_cast<const float4*>(&As[kk][ty*8+4]);
      *reinterpret_cast<float4*>(&b_[0]) = *reinterpret_cast<const float4*>(&Bs[kk][tx*8]);
      *reinterpret_cast<float4*>(&b_[4]) = *reinterpret_cast<const float4*>(&Bs[kk][tx*8+4]);
#pragma unroll
      for (int i=0;i<8;i++)
#pragma unroll
        for (int j=0;j<8;j++) acc[i][j] = fmaf(a_[i], b_[j], acc[i][j]);
    }
  }
  // epilogue: +bias +res, then row LayerNorm via width-32 shuffles (row = 32 lanes x 8 cols)
  float gg[8], bb[8];
#pragma unroll
  for (int j=0;j<8;j++){ gg[j]=lng[tx*8+j]; bb[j]=lnb[tx*8+j]; }
#pragma unroll
  for (int i=0;i<8;i++){
    const int row = bm + ty*8 + i;
    const float* rr = res + (size_t)row*N + tx*8;
    float4 r0 = *reinterpret_cast<const float4*>(rr);
    float4 r1 = *reinterpret_cast<const float4*>(rr+4);
    float v[8];
    v[0]=acc[i][0]+r0.x; v[1]=acc[i][1]+r0.y; v[2]=acc[i][2]+r0.z; v[3]=acc[i][3]+r0.w;
    v[4]=acc[i][4]+r1.x; v[5]=acc[i][5]+r1.y; v[6]=acc[i][6]+r1.z; v[7]=acc[i][7]+r1.w;
    if (BIAS){
#pragma unroll
      for (int j=0;j<8;j++) v[j] += bias[tx*8+j];
    }
    float s = 0.f;
#pragma unroll
    for (int j=0;j<8;j++) s += v[j];
#pragma unroll
    for (int o=16;o;o>>=1) s += __shfl_xor(s,o,32);
    float mean = s*(1.f/256.f);
    float s2 = 0.f;
#pragma unroll
    for (int j=0;j<8;j++){ v[j] -= mean; s2 = fmaf(v[j],v[j],s2); }
#pragma unroll
    for (int o=16;o;o>>=1) s2 += __shfl_xor(s2,o,32);
    float rstd = 1.f/sqrtf(s2*(1.f/256.f)+1e-12f);
    float outv[8];
#pragma unroll
    for (int j=0;j<8;j++) outv[j] = v[j]*rstd*gg[j]+bb[j];
    *reinterpret_cast<float4*>(C + (size_t)row*N + tx*8)     = *reinterpret_cast<float4*>(&outv[0]);
    *reinterpret_cast<float4*>(C + (size_t)row*N + tx*8 + 4) = *reinterpret_cast<float4*>(&outv[4]);
  }
}

// ---------------- fused per-(b,h) attention with edge embeddings ----------------
__global__ __launch_bounds__(128)
void k_attn(const float* __restrict__ qkv, const int* __restrict__ elab,
            const float* __restrict__ ektab, const float* __restrict__ evtab,
            const float* __restrict__ imask, float* __restrict__ ctx)
{
  __shared__ float qs[CS][CDH], ks[CS][CDH], vs[CS][CDH];
  __shared__ float at[CS][CS+1];
  __shared__ int   lab[CS*CS];
  __shared__ float im[CS];
  const int bh = blockIdx.x, b = bh >> 2, h = bh & 3;
  const int tid = threadIdx.x;
  const float* qb = qkv + (size_t)b*CS*(3*CD) + h*CDH;
  for (int idx=tid; idx<CS*CDH; idx+=128){
    int i = idx>>6, dd = idx&63;
    qs[i][dd] = qb[(size_t)i*768 + dd];
    ks[i][dd] = qb[(size_t)i*768 + CD + dd];
    vs[i][dd] = qb[(size_t)i*768 + 2*CD + dd];
  }
  for (int idx=tid; idx<CS*CS; idx+=128) lab[idx] = elab[(size_t)b*CS*CS + idx];
  if (tid < CS) im[tid] = imask[b*CS + tid];
  __syncthreads();
  if (tid < CS*CS){
    int i = tid/CS, j = tid%CS;
    int l = lab[tid];
    float accq = 0.f;
#pragma unroll
    for (int dd=0;dd<CDH;dd++) accq = fmaf(qs[i][dd], ks[j][dd], accq);
    float acce = 0.f;
    if (l > 0){
      const float* ek = ektab + (size_t)l*CDH;
#pragma unroll
      for (int dd=0;dd<CDH;dd++) acce = fmaf(qs[i][dd], ek[dd], acce);
    }
    float amv = BIGF*(im[i]*im[j]-1.f);
    at[i][j] = (accq+acce)*0.125f + amv;
  }
  __syncthreads();
  if (tid < CS){
    float m = -3.0e38f;
#pragma unroll
    for (int j=0;j<CS;j++) m = fmaxf(m, at[tid][j]);
    float e[CS]; float s = 0.f;
#pragma unroll
    for (int j=0;j<CS;j++){ e[j] = expf(at[tid][j]-m); s += e[j]; }
    float inv = 1.f/s;
#pragma unroll
    for (int j=0;j<CS;j++) at[tid][j] = e[j]*inv;
  }
  __syncthreads();
  for (int idx=tid; idx<CS*CDH; idx+=128){
    int i = idx>>6, dd = idx&63;
    float a = 0.f;
#pragma unroll
    for (int j=0;j<CS;j++){
      int l = lab[i*CS+j];
      float vv = vs[j][dd];
      if (l > 0) vv += evtab[(size_t)l*CDH + dd];
      a = fmaf(at[i][j], vv, a);
    }
    ctx[((size_t)b*CS + i)*CD + h*CDH + dd] = a;
  }
}

// ---------------- head: hm = LN(gelu(enc_out[b, mask_pos[b]])) ----------------
__global__ __launch_bounds__(256)
void k_head(const float* __restrict__ x, const int* __restrict__ mask_pos,
            const float* __restrict__ g, const float* __restrict__ bta,
            float* __restrict__ hm)
{
  __shared__ float red[8];
  const int b = blockIdx.x, d = threadIdx.x;
  float v = geluf(x[((size_t)b*CS + mask_pos[b])*CD + d]);
  float m = blk_sum(v, red)*(1.f/CD);
  float dv = v - m;
  float var = blk_sum(dv*dv, red)*(1.f/CD);
  hm[(size_t)b*CD + d] = dv/sqrtf(var+1e-7f)*g[d] + bta[d];
}

// ---------------- classifier: fc[b][c] = hm[b] . emb_row(c) + bias(c) ----------------
__global__ __launch_bounds__(256)
void k_fc(const float* __restrict__ hm, const float* __restrict__ emb,
          const float* __restrict__ fc2b, const float* __restrict__ fc3b,
          float* __restrict__ out)
{
  __shared__ alignas(16) float As[32][36];
  __shared__ alignas(16) float Bs[32][68];
  const int bn = blockIdx.x*64, bm = blockIdx.y*32;
  const int tid = threadIdx.x;
  const int tx = tid & 15, ty = tid >> 4;
  const int ar = tid >> 3, ak = (tid & 7)*4;   // A loader
  const int bnl = tid >> 2, bk8 = (tid & 3)*8; // B loader
  const int c = bn + bnl;
  const float* brow = nullptr;
  if (c < CNCLS){
    int rr = (c < CNREL) ? (3 + c) : (CVOC + (c - CNREL));
    brow = emb + (size_t)rr*CD;
  }
  float acc[2][4] = {};
  for (int k0=0;k0<CD;k0+=32){
    float4 a4 = *reinterpret_cast<const float4*>(hm + (size_t)(bm+ar)*CD + k0 + ak);
    As[ak+0][ar]=a4.x; As[ak+1][ar]=a4.y; As[ak+2][ar]=a4.z; As[ak+3][ar]=a4.w;
    float4 b0 = make_float4(0.f,0.f,0.f,0.f), b1 = make_float4(0.f,0.f,0.f,0.f);
    if (brow){
      b0 = *reinterpret_cast<const float4*>(brow + k0 + bk8);
      b1 = *reinterpret_cast<const float4*>(brow + k0 + bk8 + 4);
    }
    Bs[bk8+0][bnl]=b0.x; Bs[bk8+1][bnl]=b0.y; Bs[bk8+2][bnl]=b0.z; Bs[bk8+3][bnl]=b0.w;
    Bs[bk8+4][bnl]=b1.x; Bs[bk8+5][bnl]=b1.y; Bs[bk8+6][bnl]=b1.z; Bs[bk8+7][bnl]=b1.w;
    __syncthreads();
#pragma unroll
    for (int kk=0;kk<32;kk++){
      float a0 = As[kk][ty*2+0], a1 = As[kk][ty*2+1];
      float4 bv4 = *reinterpret_cast<const float4*>(&Bs[kk][tx*4]);
      float b_[4] = {bv4.x,bv4.y,bv4.z,bv4.w};
#pragma unroll
      for (int j=0;j<4;j++){
        acc[0][j] = fmaf(a0, b_[j], acc[0][j]);
        acc[1][j] = fmaf(a1, b_[j], acc[1][j]);
      }
    }
    __syncthreads();
  }
#pragma unroll
  for (int i=0;i<2;i++){
    const int row = bm + ty*2 + i;
#pragma unroll
    for (int j=0;j<4;j++){
      const int col = bn + tx*4 + j;
      if (col < CNCLS){
        float bias = (col < CNREL) ? fc2b[col] : fc3b[col-CNREL];
        out[(size_t)row*CNCLS + col] = acc[i][j] + bias;
      }
    }
  }
}

// ---------------- CE per row + in-place BIG mask (log_softmax is shift-invariant) --------
__global__ __launch_bounds__(256)
void k_ce(float* __restrict__ fcp, const float* __restrict__ gt,
          const int* __restrict__ mask_type, float* __restrict__ cer, float* __restrict__ cet)
{
  __shared__ float red[8];
  const int b = blockIdx.x, tid = threadIdx.x;
  float* row = fcp + (size_t)b*CNCLS;
  const float* g = gt + (size_t)b*CNCLS;
  float mx = -3.0e38f;
  for (int c=tid;c<CNREL;c+=256) mx = fmaxf(mx, row[c]);
  mx = blk_max(mx, red);
  float se=0.f, dt=0.f, gs=0.f;
  for (int c=tid;c<CNREL;c+=256){ float f=row[c], gv=g[c]; se+=expf(f-mx); dt=fmaf(gv,f,dt); gs+=gv; }
  se = blk_sum(se, red); dt = blk_sum(dt, red); gs = blk_sum(gs, red);
  if (tid==0) cer[b] = mx + logf(se) - dt/gs;
  float mx2 = -3.0e38f;
  for (int c=CNREL+tid;c<CNCLS;c+=256) mx2 = fmaxf(mx2, row[c]);
  mx2 = blk_max(mx2, red);
  float se2=0.f, dt2=0.f, gs2=0.f;
  for (int c=CNREL+tid;c<CNCLS;c+=256){ float f=row[c], gv=g[c]; se2+=expf(f-mx2); dt2=fmaf(gv,f,dt2); gs2+=gv; }
  se2 = blk_sum(se2, red); dt2 = blk_sum(dt2, red); gs2 = blk_sum(gs2, red);
  if (tid==0) cet[b] = mx2 + logf(se2) - dt2/gs2;
  __syncthreads();
  if (mask_type[b]==1){ for (int c=tid;c<CNREL;c+=256) row[c] -= BIGF; }
  else                { for (int c=CNREL+tid;c<CNCLS;c+=256) row[c] -= BIGF; }
}

__global__ __launch_bounds__(256)
void k_loss(const float* __restrict__ cer, const float* __restrict__ cet,
            const int* __restrict__ mask_type, float* __restrict__ outp)
{
  __shared__ float red[8];
  const int tid = threadIdx.x;
  float sr=0.f, st=0.f, nr=0.f, nt=0.f;
  for (int b=tid;b<CB;b+=256){
    int mt = mask_type[b];
    if (mt==-1){ sr += cer[b]; nr += 1.f; }
    else if (mt==1){ st += cet[b]; nt += 1.f; }
  }
  sr = blk_sum(sr, red); st = blk_sum(st, red);
  nr = blk_sum(nr, red); nt = blk_sum(nt, red);
  if (tid==0) outp[0] = sr/fmaxf(nr,1.f) + st/fmaxf(nt,1.f);
}

// ---------------- host orchestration ----------------
extern "C" void kernel_launch(void* const* d_in, const int* in_sizes, int n_in,
                              void* d_out, int out_size, void* d_ws, size_t ws_size,
                              hipStream_t stream)
{
  (void)in_sizes; (void)n_in; (void)out_size; (void)ws_size;
  const int*   input_ids  = (const int*)  d_in[0];
  const float* input_mask = (const float*)d_in[1];
  const int*   edge_labels= (const int*)  d_in[2];
  const int*   mask_pos   = (const int*)  d_in[3];
  const int*   mask_type  = (const int*)  d_in[5];
  const int*   ent_types  = (const int*)  d_in[6];
  const float* gtruth     = (const float*)d_in[7];
  const int*   l2m        = (const int*)  d_in[8];
  const float* emb        = (const float*)d_in[9];
  const float* ln1g=(const float*)d_in[10], *ln1b=(const float*)d_in[11];
  const float* ln2g=(const float*)d_in[12], *ln2b=(const float*)d_in[13];
  const float* fc2b=(const float*)d_in[14], *fc3b=(const float*)d_in[15];
  const float* ektab=(const float*)d_in[16], *evtab=(const float*)d_in[17];
  const float* g1W=(const float*)d_in[18], *g1as=(const float*)d_in[19], *g1ad=(const float*)d_in[20];
  const float* g2W=(const float*)d_in[21], *g2as=(const float*)d_in[22], *g2ad=(const float*)d_in[23];
  const float* wqkv=(const float*)d_in[24], *wo=(const float*)d_in[25];
  const float* el1g=(const float*)d_in[26], *el1b=(const float*)d_in[27];
  const float* w1=(const float*)d_in[28], *b1=(const float*)d_in[29];
  const float* w2=(const float*)d_in[30], *b2=(const float*)d_in[31];
  const float* el2g=(const float*)d_in[32], *el2b=(const float*)d_in[33];

  char* wsb = (char*)d_ws;
  size_t off = 0;
  auto alloc = [&](size_t bytes)->char*{
    char* p = wsb + off;
    off += (bytes + 255) & ~(size_t)255;
    return p;
  };
  int*   itt  = (int*)  alloc((size_t)NN*CSP*4);
  float* TW1  = (float*)alloc((size_t)NTAB*CD*4);
  float* Ts1  = (float*)alloc(NTAB*4);
  float* Tt1  = (float*)alloc(NTAB*4);
  float* TW2  = (float*)alloc((size_t)NTAB*CD*4);
  float* Ts2  = (float*)alloc(NTAB*4);
  float* Tt2  = (float*)alloc(NTAB*4);
  float* g1o  = (float*)alloc((size_t)NN*CD*4);   // g1; later reused as g2
  float* G1W  = (float*)alloc((size_t)NN*CD*4);
  float* G1s  = (float*)alloc(NN*4);
  float* G1t  = (float*)alloc(NN*4);
  float* G1rs = (float*)alloc(NN*4);
  float* xb   = (float*)alloc((size_t)NSR*CD*4);
  float* qkvb = (float*)alloc((size_t)NSR*3*CD*4);
  float* ctxb = (float*)alloc((size_t)NSR*CD*4);
  float* cer  = (float*)alloc(CB*4);
  float* cet  = (float*)alloc(CB*4);
  float* ffh  = qkvb;   // alias: qkv dead once attn has consumed it
  float* g2o  = g1o;    // alias: raw g1 dead after k_gemm128/k_g1red
  float* hm   = ctxb;   // alias: ctx dead after the encoder

  float* dout = (float*)d_out;
  float* fcp  = dout + 1;   // fc_out; dout[0] = loss

  // ---- GAT pipeline ----
  k_typeprep<<<dim3((NN*CSP+255)/256),dim3(256),0,stream>>>(input_ids, ent_types, itt);
  k_tables<<<dim3(NTAB),dim3(256),0,stream>>>(emb, g1W, g1as, g1ad, TW1, Ts1, Tt1);
  k_tables<<<dim3(NTAB),dim3(256),0,stream>>>(emb, g2W, g2as, g2ad, TW2, Ts2, Tt2);
  k_gat<10><<<dim3(NN),dim3(128),0,stream>>>(itt, TW1, Ts1, Tt1,
        nullptr, nullptr, nullptr, nullptr, nullptr,
        g1W + CD*CD, g1as + CD, g1ad + CD, g1o);
  k_gemm128<0,false><<<dim3(2,NN/128),dim3(256),0,stream>>>(g1o, g2W, nullptr, G1W, NN, 256, 256);
  k_g1red<<<dim3(NN),dim3(256),0,stream>>>(g1o, G1W, g2as, g2ad, G1s, G1t, G1rs);
  k_gat<15><<<dim3(NN),dim3(128),0,stream>>>(itt, TW2, Ts2, Tt2,
        G1W, G1s, G1t, G1rs, l2m,
        g2W + CD*CD, g2as + CD, g2ad + CD, g2o);
  k_x0<<<dim3(NSR),dim3(256),0,stream>>>(input_ids, mask_pos, mask_type, emb, g2o, ln1g, ln1b, xb);

  // ---- encoder (12 layers) ----
  for (int l=0;l<CL;l++){
    const float* wqkv_l = wqkv + (size_t)l*CD*3*CD;
    const float* wo_l   = wo   + (size_t)l*CD*CD;
    const float* w1_l   = w1   + (size_t)l*CD*512;
    const float* b1_l   = b1   + (size_t)l*512;
    const float* w2_l   = w2   + (size_t)l*512*CD;
    const float* b2_l   = b2   + (size_t)l*CD;
    k_gemm128<0,false><<<dim3(6,NSR/128),dim3(256),0,stream>>>(xb, wqkv_l, nullptr, qkvb, NSR, 768, 256);
    k_attn<<<dim3(CB*CH),dim3(128),0,stream>>>(qkvb, edge_labels, ektab, evtab, input_mask, ctxb);
    k_gemm64ln<false><<<dim3(NSR/64),dim3(256),0,stream>>>(ctxb, wo_l, nullptr, xb,
        el1g + (size_t)l*CD, el1b + (size_t)l*CD, xb, NSR, 256);
    k_gemm128<1,true><<<dim3(4,NSR/128),dim3(256),0,stream>>>(xb, w1_l, b1_l, ffh, NSR, 512, 256);
    k_gemm64ln<true><<<dim3(NSR/64),dim3(256),0,stream>>>(ffh, w2_l, b2_l, xb,
        el2g + (size_t)l*CD, el2b + (size_t)l*CD, xb, NSR, 512);
  }

  // ---- head / classifier / loss ----
  k_head<<<dim3(CB),dim3(256),0,stream>>>(xb, mask_pos, ln2g, ln2b, hm);
  k_fc<<<dim3((CNCLS+63)/64, CB/32),dim3(256),0,stream>>>(hm, emb, fc2b, fc3b, fcp);
  k_ce<<<dim3(CB),dim3(256),0,stream>>>(fcp, gtruth, mask_type, cer, cet);
  k_loss<<<dim3(1),dim3(256),0,stream>>>(cer, cet, mask_type, dout);
}

// Round 3
// 4265.546 us; speedup vs baseline: 1.7174x; 1.7174x over previous
//
#include <hip/hip_runtime.h>
#include <math.h>

// ---------------- problem constants ----------------
constexpr int CB=2048, CMA=6, CS=11, CSP=10, CD=256, CH=4, CDH=64, CL=12;
constexpr int CNREL=500, CNTYPE=1000, CNODE=100000, CVOC=99000, CNCLS=1500;
constexpr int NN  = CB*CMA;     // 12288 GAT nodes
constexpr int NSR = CB*CS;      // 22528 sequence rows
constexpr int NTAB= 3+CNTYPE;   // 1003 distinct type-embedding rows
constexpr int GCH = 2048;       // GAT node chunk
constexpr float BIGF = 1000000.0f;

typedef __attribute__((ext_vector_type(8))) short short8v;
typedef __attribute__((ext_vector_type(4))) float f32x4;
typedef unsigned short ushort;

__device__ __forceinline__ float lreluf(float x){ return x>=0.f ? x : 0.2f*x; }
__device__ __forceinline__ float eluf1(float x){ return x>0.f ? x : expm1f(x); }
__device__ __forceinline__ float geluf(float x){ return 0.5f*x*(1.f+erff(x*0.70710678118654752f)); }

__device__ __forceinline__ ushort f2bf(float v){
  unsigned u = __float_as_uint(v);
  unsigned r = (u + 0x7FFFu + ((u>>16)&1u)) >> 16;
  return (ushort)r;
}
__device__ __forceinline__ float bf2f(ushort s){ return __uint_as_float(((unsigned)s)<<16); }
__device__ __forceinline__ void split2(float v, ushort& h, ushort& l){
  h = f2bf(v); l = f2bf(v - bf2f(h));
}

// block=256 reductions (4 waves)
__device__ __forceinline__ float blk_sum(float v, float* red){
#pragma unroll
  for (int o=32;o;o>>=1) v += __shfl_down(v,o,64);
  __syncthreads();
  if ((threadIdx.x&63)==0) red[threadIdx.x>>6]=v;
  __syncthreads();
  return red[0]+red[1]+red[2]+red[3];
}
__device__ __forceinline__ float blk_max(float v, float* red){
#pragma unroll
  for (int o=32;o;o>>=1) v = fmaxf(v,__shfl_down(v,o,64));
  __syncthreads();
  if ((threadIdx.x&63)==0) red[threadIdx.x>>6]=v;
  __syncthreads();
  return fmaxf(fmaxf(red[0],red[1]),fmaxf(red[2],red[3]));
}

// ---------------- weight split+transpose: f32 [K][N] -> bf16 hi/lo [N][K] ----------------
__global__ __launch_bounds__(256)
void k_wsplit(const float* __restrict__ src0, ushort* __restrict__ dst0, int K, int N)
{
  __shared__ float t[32][33];
  const int z = blockIdx.z;
  const float* src = src0 + (size_t)z*K*N;
  ushort* hi = dst0 + (size_t)z*2*K*N;
  ushort* lo = hi + (size_t)K*N;
  const int nb = blockIdx.x*32, kb = blockIdx.y*32;
  const int r = threadIdx.x>>5, c = threadIdx.x&31;
#pragma unroll
  for (int i=0;i<4;i++)
    t[r+8*i][c] = src[(size_t)(kb + r + 8*i)*N + nb + c];
  __syncthreads();
#pragma unroll
  for (int i=0;i<4;i++){
    int lin = threadIdx.x + 256*i;
    int n = lin>>5, k = lin&31;
    float v = t[k][n];
    ushort h, l; split2(v, h, l);
    hi[(size_t)(nb+n)*K + kb + k] = h;
    lo[(size_t)(nb+n)*K + kb + k] = l;
  }
}

// ---------------- bf16x3 MFMA GEMM, tile 64x256, BK=32 ----------------
// A: [M][K] bf16 hi/lo. B: [N][K] bf16 hi/lo (pre-transposed). C = A@B.
// EPI 0: C f32. EPI 1: Chi/Clo = split(gelu(C+bias)). EPI 2 (N==256): f32+split LN(C(+bias)+res).
template<int EPI, bool BIAS>
__global__ __launch_bounds__(256,2)
void k_mgemm(const ushort* __restrict__ Ahi, const ushort* __restrict__ Alo,
             const ushort* __restrict__ Bhi, const ushort* __restrict__ Blo,
             const float* __restrict__ bias, const float* __restrict__ res,
             const float* __restrict__ lng, const float* __restrict__ lnb,
             float* __restrict__ C, ushort* __restrict__ Chi, ushort* __restrict__ Clo,
             int M, int N, int K)
{
  constexpr int LDK = 40;  // padded k-stride (ushorts): 80B, 2-way-conflict-free frag reads
  __shared__ alignas(16) ushort Ash[2][64*LDK];
  __shared__ alignas(16) ushort Bsh[2][256*LDK];
  const int tid = threadIdx.x;
  const int wv = tid>>6, ln = tid&63;
  const int fr = ln&15, fq = ln>>4;
  const int bm = blockIdx.y*64, bn = blockIdx.x*256;
  f32x4 acc[4][4];
#pragma unroll
  for (int m=0;m<4;m++)
#pragma unroll
    for (int n=0;n<4;n++) acc[m][n] = (f32x4){0.f,0.f,0.f,0.f};

  for (int k0=0;k0<K;k0+=32){
    __syncthreads();
#pragma unroll
    for (int s=0;s<10;s++){
      int u = tid + s*256;
      const ushort* gp; ushort* lp;
      if (u < 512){
        int hl = u>>8, r = (u>>2)&63, ko = (u&3)*8;
        gp = (hl ? Alo : Ahi) + (size_t)(bm+r)*K + k0 + ko;
        lp = &Ash[hl][r*LDK + ko];
      } else {
        int u2 = u - 512;
        int hl = u2>>10, r = (u2>>2)&255, ko = (u2&3)*8;
        gp = (hl ? Blo : Bhi) + (size_t)(bn+r)*K + k0 + ko;
        lp = &Bsh[hl][r*LDK + ko];
      }
      *(short8v*)lp = *(const short8v*)gp;
    }
    __syncthreads();
    short8v ah[4], al[4], bh[4], bl[4];
#pragma unroll
    for (int m=0;m<4;m++){
      ah[m] = *(const short8v*)&Ash[0][(m*16+fr)*LDK + fq*8];
      al[m] = *(const short8v*)&Ash[1][(m*16+fr)*LDK + fq*8];
    }
#pragma unroll
    for (int n=0;n<4;n++){
      bh[n] = *(const short8v*)&Bsh[0][(wv*64+n*16+fr)*LDK + fq*8];
      bl[n] = *(const short8v*)&Bsh[1][(wv*64+n*16+fr)*LDK + fq*8];
    }
#pragma unroll
    for (int m=0;m<4;m++)
#pragma unroll
      for (int n=0;n<4;n++){
        acc[m][n] = __builtin_amdgcn_mfma_f32_16x16x32_bf16(ah[m], bh[n], acc[m][n], 0,0,0);
        acc[m][n] = __builtin_amdgcn_mfma_f32_16x16x32_bf16(ah[m], bl[n], acc[m][n], 0,0,0);
        acc[m][n] = __builtin_amdgcn_mfma_f32_16x16x32_bf16(al[m], bh[n], acc[m][n], 0,0,0);
      }
  }

  // lane owns: row = bm + m*16 + fq*4 + j ; col = bn + wv*64 + n*16 + fr
  if constexpr (EPI == 0){
#pragma unroll
    for (int m=0;m<4;m++)
#pragma unroll
      for (int j=0;j<4;j++){
        size_t ro = (size_t)(bm + m*16 + fq*4 + j)*N;
#pragma unroll
        for (int n=0;n<4;n++)
          C[ro + bn + wv*64 + n*16 + fr] = acc[m][n][j];
      }
  }
  if constexpr (EPI == 1){
    float bcol[4];
#pragma unroll
    for (int n=0;n<4;n++) bcol[n] = BIAS ? bias[bn + wv*64 + n*16 + fr] : 0.f;
#pragma unroll
    for (int m=0;m<4;m++)
#pragma unroll
      for (int j=0;j<4;j++){
        size_t ro = (size_t)(bm + m*16 + fq*4 + j)*N;
#pragma unroll
        for (int n=0;n<4;n++){
          float v = geluf(acc[m][n][j] + bcol[n]);
          ushort hh,ll; split2(v,hh,ll);
          size_t o = ro + bn + wv*64 + n*16 + fr;
          Chi[o]=hh; Clo[o]=ll;
        }
      }
  }
  if constexpr (EPI == 2){
    float bcol[4], gcol[4], bbcol[4];
#pragma unroll
    for (int n=0;n<4;n++){
      int col = wv*64 + n*16 + fr;
      bcol[n] = BIAS ? bias[col] : 0.f;
      gcol[n] = lng[col]; bbcol[n] = lnb[col];
    }
    float sum_[4][4], sq_[4][4];
#pragma unroll
    for (int m=0;m<4;m++)
#pragma unroll
      for (int j=0;j<4;j++){
        size_t ro = (size_t)(bm + m*16 + fq*4 + j)*256;
        float s=0.f, q=0.f;
#pragma unroll
        for (int n=0;n<4;n++){
          float f = acc[m][n][j] + bcol[n] + res[ro + wv*64 + n*16 + fr];
          acc[m][n][j] = f; s += f; q = fmaf(f,f,q);
        }
#pragma unroll
        for (int o=1;o<16;o<<=1){ s += __shfl_xor(s,o,64); q += __shfl_xor(q,o,64); }
        sum_[m][j]=s; sq_[m][j]=q;
      }
    __syncthreads();
    float* redS = (float*)&Ash[0][0];   // 512 f32 = 2KB, fits in Ash
    if (fr==0){
#pragma unroll
      for (int m=0;m<4;m++)
#pragma unroll
        for (int j=0;j<4;j++){
          int r = m*16 + fq*4 + j;
          redS[wv*64 + r] = sum_[m][j];
          redS[256 + wv*64 + r] = sq_[m][j];
        }
    }
    __syncthreads();
#pragma unroll
    for (int m=0;m<4;m++)
#pragma unroll
      for (int j=0;j<4;j++){
        int r = m*16 + fq*4 + j;
        float S = redS[r] + redS[64+r] + redS[128+r] + redS[192+r];
        float Q = redS[256+r] + redS[320+r] + redS[384+r] + redS[448+r];
        float mean = S*(1.f/256.f);
        float var  = Q*(1.f/256.f) - mean*mean;
        float rstd = 1.f/sqrtf(var + 1e-12f);
        size_t ro = (size_t)(bm + r)*256;
#pragma unroll
        for (int n=0;n<4;n++){
          int col = wv*64 + n*16 + fr;
          float o = (acc[m][n][j] - mean)*rstd*gcol[n] + bbcol[n];
          C[ro + col] = o;
          ushort hh,ll; split2(o,hh,ll);
          Chi[ro+col]=hh; Clo[ro+col]=ll;
        }
      }
  }
}

// ---------------- type prep: itt[n][sp] ----------------
__global__ __launch_bounds__(256)
void k_typeprep(const int* __restrict__ input_ids, const int* __restrict__ ent_types,
                int* __restrict__ itt)
{
  int idx = blockIdx.x*256 + threadIdx.x;
  if (idx >= NN*CSP) return;
  int n = idx / CSP, sp = idx % CSP;
  int b = n / CMA, ma = n % CMA;
  int id = input_ids[b*CS + 2*ma] - CNREL;
  itt[idx] = (id < 3) ? id : ent_types[(size_t)(id-3)*(CSP+1) + sp + 1];
}

// ---------------- distinct-row table: TW = T@W, Ts=TW@a_src, Tt=TW@a_dst ----------------
__global__ __launch_bounds__(256)
void k_tables(const float* __restrict__ emb, const float* __restrict__ W,
              const float* __restrict__ asrc, const float* __restrict__ adst,
              float* __restrict__ TW, float* __restrict__ Ts, float* __restrict__ Tt)
{
  __shared__ float row[CD];
  __shared__ float red[8];
  const int r = blockIdx.x, d = threadIdx.x;
  const int nrow = (r<3) ? r : (CVOC + (r-3));
  row[d] = emb[(size_t)nrow*CD + d];
  __syncthreads();
  float acc = 0.f;
  for (int k=0;k<CD;k+=4){
    const float4 hv = *reinterpret_cast<const float4*>(&row[k]);
    acc = fmaf(hv.x, W[(size_t)(k+0)*CD+d],
          fmaf(hv.y, W[(size_t)(k+1)*CD+d],
          fmaf(hv.z, W[(size_t)(k+2)*CD+d],
          fmaf(hv.w, W[(size_t)(k+3)*CD+d], acc))));
  }
  TW[(size_t)r*CD+d] = acc;
  float s = blk_sum(acc*asrc[d], red);
  float t = blk_sum(acc*adst[d], red);
  if (d==0){ Ts[r]=s; Tt[r]=t; }
}

// ---------------- f32 128x128 GEMM (kept for GW = g1@W) ----------------
template<int ACT, bool BIAS>
__global__ __launch_bounds__(256)
void k_gemm128(const float* __restrict__ A, const float* __restrict__ Bm,
               const float* __restrict__ bias, float* __restrict__ C,
               int M, int N, int K)
{
  __shared__ alignas(16) float As[16][132];
  __shared__ alignas(16) float Bs[16][132];
  const int tid = threadIdx.x;
  const int bn = blockIdx.x*128, bm = blockIdx.y*128;
  const int tx = tid & 15, ty = tid >> 4;
  const int ar = tid >> 1, ak = (tid & 1)*8;
  const int bk = tid >> 4, bnl = (tid & 15)*8;
  const float* Ap = A + (size_t)(bm + ar)*K + ak;
  const float* Bp = Bm + (size_t)bk*N + bn + bnl;
  float acc[8][8] = {};
  for (int k0=0; k0<K; k0+=16){
    float4 av0 = *reinterpret_cast<const float4*>(Ap + k0);
    float4 av1 = *reinterpret_cast<const float4*>(Ap + k0 + 4);
    float4 bv0 = *reinterpret_cast<const float4*>(Bp + (size_t)k0*N);
    float4 bv1 = *reinterpret_cast<const float4*>(Bp + (size_t)k0*N + 4);
    __syncthreads();
    As[ak+0][ar]=av0.x; As[ak+1][ar]=av0.y; As[ak+2][ar]=av0.z; As[ak+3][ar]=av0.w;
    As[ak+4][ar]=av1.x; As[ak+5][ar]=av1.y; As[ak+6][ar]=av1.z; As[ak+7][ar]=av1.w;
    *reinterpret_cast<float4*>(&Bs[bk][bnl])   = bv0;
    *reinterpret_cast<float4*>(&Bs[bk][bnl+4]) = bv1;
    __syncthreads();
#pragma unroll
    for (int kk=0; kk<16; kk++){
      float a_[8], b_[8];
      *reinterpret_cast<float4*>(&a_[0]) = *reinterpret_cast<const float4*>(&As[kk][ty*8]);
      *reinterpret_cast<float4*>(&a_[4]) = *reinterpret_cast<const float4*>(&As[kk][ty*8+4]);
      *reinterpret_cast<float4*>(&b_[0]) = *reinterpret_cast<const float4*>(&Bs[kk][tx*8]);
      *reinterpret_cast<float4*>(&b_[4]) = *reinterpret_cast<const float4*>(&Bs[kk][tx*8+4]);
#pragma unroll
      for (int i=0;i<8;i++)
#pragma unroll
        for (int j=0;j<8;j++) acc[i][j] = fmaf(a_[i], b_[j], acc[i][j]);
    }
  }
#pragma unroll
  for (int i=0;i<8;i++){
    const int row = bm + ty*8 + i;
    float outv[8];
#pragma unroll
    for (int j=0;j<8;j++){
      float v = acc[i][j];
      if (BIAS) v += bias[bn + tx*8 + j];
      if (ACT==1) v = geluf(v);
      outv[j] = v;
    }
    *reinterpret_cast<float4*>(C + (size_t)row*N + bn + tx*8)     = *reinterpret_cast<float4*>(&outv[0]);
    *reinterpret_cast<float4*>(C + (size_t)row*N + bn + tx*8 + 4) = *reinterpret_cast<float4*>(&outv[4]);
  }
}

// ---------------- g1 reductions for GAT2 gather ----------------
__global__ __launch_bounds__(256)
void k_g1red(const float* __restrict__ g1, const float* __restrict__ GW,
             const float* __restrict__ asrc, const float* __restrict__ adst,
             float* __restrict__ Gs, float* __restrict__ Gt, float* __restrict__ Grs)
{
  __shared__ float red[8];
  const int n = blockIdx.x, d = threadIdx.x;
  float w = GW[(size_t)n*CD + d];
  float v = g1[(size_t)n*CD + d];
  float s  = blk_sum(w*asrc[d], red);
  float t  = blk_sum(w*adst[d], red);
  float rs = blk_sum(v, red);
  if (d==0){ Gs[n]=s; Gt[n]=t; Grs[n]=rs; }
}

// ---------------- GAT masked softmax (thread i owns row i) ----------------
template<int P>
__device__ __forceinline__ void gat_softmax(float (*att)[P+1], const float* sA,
                                            const float* tA, const int* sg)
{
  const int i = threadIdx.x;
  if (i < P){
    if (sg[i]){
      float si = sA[i];
      float e[P];
      float m = -3.0e38f;
#pragma unroll
      for (int j=0;j<P;j++){
        e[j] = 0.f;
        if (sg[j]){ e[j] = lreluf(si + tA[j]); m = fmaxf(m, e[j]); }
      }
      float s = 0.f;
#pragma unroll
      for (int j=0;j<P;j++){
        float w = sg[j] ? expf(e[j]-m) : 0.f;
        att[i][j] = w; s += w;
      }
      float inv = 1.f/s;
#pragma unroll
      for (int j=0;j<P;j++) att[i][j] *= inv;
    } else {
#pragma unroll
      for (int j=0;j<P;j++) att[i][j] = 0.f;
    }
  }
}

// ---------------- GAT stage A: gather + softmax1 + h1 = elu(att@hW) -> bf16 split -------
template<int P>
__global__ __launch_bounds__(256)
void k_gatl1(int nbase, const int* __restrict__ itt,
             const float* __restrict__ TW, const float* __restrict__ Ts, const float* __restrict__ Tt,
             const float* __restrict__ GW, const float* __restrict__ Gs, const float* __restrict__ Gt,
             const float* __restrict__ Grs, const int* __restrict__ l2m,
             ushort* __restrict__ H1hi, ushort* __restrict__ H1lo)
{
  __shared__ float hW[P][CD];
  __shared__ float att[P][P+1];
  __shared__ float sA[P], tA[P];
  __shared__ int sg[P], ridx[P];
  const int n = nbase + blockIdx.x;
  const int d = threadIdx.x;
  if (d < P){
    if (d < CSP){
      int it = itt[n*CSP + d];
      int r = (it < 3) ? it : (it - (CVOC - 3));
      ridx[d]=r; sg[d]=(it>0); sA[d]=Ts[r]; tA[d]=Tt[r];
    } else {
      int ma = n % CMA;
      int m = l2m[ma*(CMA-1) + (d - CSP)];
      int nb = (n / CMA)*CMA + m;
      ridx[d]=nb; sg[d]=(Grs[nb]!=0.f); sA[d]=Gs[nb]; tA[d]=Gt[nb];
    }
  }
  __syncthreads();
#pragma unroll
  for (int i=0;i<P;i++){
    const float* src = (i<CSP) ? TW : GW;
    hW[i][d] = src[(size_t)ridx[i]*CD + d];
  }
  __syncthreads();
  gat_softmax<P>(att, sA, tA, sg);
  __syncthreads();
  float h[P];
#pragma unroll
  for (int i=0;i<P;i++) h[i]=0.f;
#pragma unroll
  for (int j=0;j<P;j++){
    float w = hW[j][d];
#pragma unroll
    for (int i=0;i<P;i++) h[i] = fmaf(att[i][j], w, h[i]);
  }
  size_t rb = ((size_t)blockIdx.x*P)*CD + d;
#pragma unroll
  for (int i=0;i<P;i++){
    float e = eluf1(h[i]);
    ushort hh,ll; split2(e,hh,ll);
    H1hi[rb + (size_t)i*CD] = hh;
    H1lo[rb + (size_t)i*CD] = ll;
  }
}

// ---------------- GAT stage B: softmax2 over Z + masked mean of elu(att@Z) --------------
template<int P>
__global__ __launch_bounds__(256)
void k_gatl2(int nbase, const int* __restrict__ itt, const float* __restrict__ Grs,
             const int* __restrict__ l2m, const float* __restrict__ Z,
             const float* __restrict__ as2, const float* __restrict__ ad2,
             float* __restrict__ gout)
{
  __shared__ float zb[P][CD];
  __shared__ float att[P][P+1];
  __shared__ float sA[P], tA[P];
  __shared__ int sg[P];
  const int n = nbase + blockIdx.x;
  const int d = threadIdx.x;
  size_t zrow = (size_t)blockIdx.x*P*CD;
#pragma unroll
  for (int i=0;i<P;i++) zb[i][d] = Z[zrow + (size_t)i*CD + d];
  if (d < P){
    if (d < CSP) sg[d] = (itt[n*CSP + d] > 0);
    else {
      int ma = n % CMA;
      int m = l2m[ma*(CMA-1) + (d - CSP)];
      int nb = (n / CMA)*CMA + m;
      sg[d] = (Grs[nb] != 0.f);
    }
  }
  __syncthreads();
  {
    int i = d>>4, l = d&15;
    if (i < P){
      float ps=0.f, pt=0.f;
      for (int dd=l; dd<CD; dd+=16){
        float w = zb[i][dd];
        ps = fmaf(w, as2[dd], ps);
        pt = fmaf(w, ad2[dd], pt);
      }
#pragma unroll
      for (int o=8;o;o>>=1){ ps += __shfl_down(ps,o,16); pt += __shfl_down(pt,o,16); }
      if (l==0){ sA[i]=ps; tA[i]=pt; }
    }
  }
  __syncthreads();
  gat_softmax<P>(att, sA, tA, sg);
  __syncthreads();
  float x[P];
#pragma unroll
  for (int i=0;i<P;i++) x[i]=0.f;
#pragma unroll
  for (int j=0;j<P;j++){
    float w = zb[j][d];
#pragma unroll
    for (int i=0;i<P;i++) x[i] = fmaf(att[i][j], w, x[i]);
  }
  float den=0.f;
#pragma unroll
  for (int i=0;i<P;i++) den += (float)sg[i];
  den = fmaxf(den,1.f);
  float o=0.f;
#pragma unroll
  for (int i=0;i<P;i++) if (sg[i]) o += eluf1(x[i]);
  gout[(size_t)n*CD + d] = o/den;
}

// ---------------- build x0 (+ bf16 split) ----------------
__global__ __launch_bounds__(256)
void k_x0(const int* __restrict__ input_ids, const int* __restrict__ mask_pos,
          const int* __restrict__ mask_type, const float* __restrict__ emb,
          const float* __restrict__ g2, const float* __restrict__ g,
          const float* __restrict__ bta, float* __restrict__ x,
          ushort* __restrict__ xhi, ushort* __restrict__ xlo)
{
  __shared__ float red[8];
  const int row = blockIdx.x;
  const int b = row / CS, s = row % CS;
  const int d = threadIdx.x;
  float val;
  if (s == mask_pos[b]){
    int mm = (mask_type[b]==1) ? 2 : 1;
    val = emb[(size_t)mm*CD + d];
  } else if ((s & 1) == 0){
    val = g2[(size_t)(b*CMA + (s>>1))*CD + d];
  } else {
    float v = emb[(size_t)input_ids[row]*CD + d];
    float m = blk_sum(v, red)*(1.f/CD);
    float dv = v - m;
    float var = blk_sum(dv*dv, red)*(1.f/CD);
    val = dv/sqrtf(var+1e-12f)*g[d] + bta[d];
  }
  size_t o = (size_t)row*CD + d;
  x[o] = val;
  ushort hh,ll; split2(val,hh,ll);
  xhi[o]=hh; xlo[o]=ll;
}

// ---------------- fused per-(b,h) attention, bf16-split ctx output ----------------
__global__ __launch_bounds__(128)
void k_attn(const float* __restrict__ qkv, const int* __restrict__ elab,
            const float* __restrict__ ektab, const float* __restrict__ evtab,
            const float* __restrict__ imask, ushort* __restrict__ ctxhi,
            ushort* __restrict__ ctxlo)
{
  __shared__ float qs[CS][CDH], ks[CS][CDH], vs[CS][CDH];
  __shared__ float at[CS][CS+1];
  __shared__ int   lab[CS*CS];
  __shared__ float im[CS];
  const int bh = blockIdx.x, b = bh >> 2, h = bh & 3;
  const int tid = threadIdx.x;
  const float* qb = qkv + (size_t)b*CS*(3*CD) + h*CDH;
  for (int idx=tid; idx<CS*CDH; idx+=128){
    int i = idx>>6, dd = idx&63;
    qs[i][dd] = qb[(size_t)i*768 + dd];
    ks[i][dd] = qb[(size_t)i*768 + CD + dd];
    vs[i][dd] = qb[(size_t)i*768 + 2*CD + dd];
  }
  for (int idx=tid; idx<CS*CS; idx+=128) lab[idx] = elab[(size_t)b*CS*CS + idx];
  if (tid < CS) im[tid] = imask[b*CS + tid];
  __syncthreads();
  if (tid < CS*CS){
    int i = tid/CS, j = tid%CS;
    int l = lab[tid];
    float accq = 0.f;
#pragma unroll
    for (int dd=0;dd<CDH;dd++) accq = fmaf(qs[i][dd], ks[j][dd], accq);
    float acce = 0.f;
    if (l > 0){
      const float* ek = ektab + (size_t)l*CDH;
#pragma unroll
      for (int dd=0;dd<CDH;dd++) acce = fmaf(qs[i][dd], ek[dd], acce);
    }
    float amv = BIGF*(im[i]*im[j]-1.f);
    at[i][j] = (accq+acce)*0.125f + amv;
  }
  __syncthreads();
  if (tid < CS){
    float m = -3.0e38f;
#pragma unroll
    for (int j=0;j<CS;j++) m = fmaxf(m, at[tid][j]);
    float e[CS]; float s = 0.f;
#pragma unroll
    for (int j=0;j<CS;j++){ e[j] = expf(at[tid][j]-m); s += e[j]; }
    float inv = 1.f/s;
#pragma unroll
    for (int j=0;j<CS;j++) at[tid][j] = e[j]*inv;
  }
  __syncthreads();
  for (int idx=tid; idx<CS*CDH; idx+=128){
    int i = idx>>6, dd = idx&63;
    float a = 0.f;
#pragma unroll
    for (int j=0;j<CS;j++){
      int l = lab[i*CS+j];
      float vv = vs[j][dd];
      if (l > 0) vv += evtab[(size_t)l*CDH + dd];
      a = fmaf(at[i][j], vv, a);
    }
    size_t o = ((size_t)b*CS + i)*CD + h*CDH + dd;
    ushort hh,ll; split2(a,hh,ll);
    ctxhi[o]=hh; ctxlo[o]=ll;
  }
}

// ---------------- head: hm = LN(gelu(enc_out[b, mask_pos[b]])) ----------------
__global__ __launch_bounds__(256)
void k_head(const float* __restrict__ x, const int* __restrict__ mask_pos,
            const float* __restrict__ g, const float* __restrict__ bta,
            float* __restrict__ hm)
{
  __shared__ float red[8];
  const int b = blockIdx.x, d = threadIdx.x;
  float v = geluf(x[((size_t)b*CS + mask_pos[b])*CD + d]);
  float m = blk_sum(v, red)*(1.f/CD);
  float dv = v - m;
  float var = blk_sum(dv*dv, red)*(1.f/CD);
  hm[(size_t)b*CD + d] = dv/sqrtf(var+1e-7f)*g[d] + bta[d];
}

// ---------------- classifier ----------------
__global__ __launch_bounds__(256)
void k_fc(const float* __restrict__ hm, const float* __restrict__ emb,
          const float* __restrict__ fc2b, const float* __restrict__ fc3b,
          float* __restrict__ out)
{
  __shared__ alignas(16) float As[32][36];
  __shared__ alignas(16) float Bs[32][68];
  const int bn = blockIdx.x*64, bm = blockIdx.y*32;
  const int tid = threadIdx.x;
  const int tx = tid & 15, ty = tid >> 4;
  const int ar = tid >> 3, ak = (tid & 7)*4;
  const int bnl = tid >> 2, bk8 = (tid & 3)*8;
  const int c = bn + bnl;
  const float* brow = nullptr;
  if (c < CNCLS){
    int rr = (c < CNREL) ? (3 + c) : (CVOC + (c - CNREL));
    brow = emb + (size_t)rr*CD;
  }
  float acc[2][4] = {};
  for (int k0=0;k0<CD;k0+=32){
    float4 a4 = *reinterpret_cast<const float4*>(hm + (size_t)(bm+ar)*CD + k0 + ak);
    As[ak+0][ar]=a4.x; As[ak+1][ar]=a4.y; As[ak+2][ar]=a4.z; As[ak+3][ar]=a4.w;
    float4 b0 = make_float4(0.f,0.f,0.f,0.f), b1 = make_float4(0.f,0.f,0.f,0.f);
    if (brow){
      b0 = *reinterpret_cast<const float4*>(brow + k0 + bk8);
      b1 = *reinterpret_cast<const float4*>(brow + k0 + bk8 + 4);
    }
    Bs[bk8+0][bnl]=b0.x; Bs[bk8+1][bnl]=b0.y; Bs[bk8+2][bnl]=b0.z; Bs[bk8+3][bnl]=b0.w;
    Bs[bk8+4][bnl]=b1.x; Bs[bk8+5][bnl]=b1.y; Bs[bk8+6][bnl]=b1.z; Bs[bk8+7][bnl]=b1.w;
    __syncthreads();
#pragma unroll
    for (int kk=0;kk<32;kk++){
      float a0 = As[kk][ty*2+0], a1 = As[kk][ty*2+1];
      float4 bv4 = *reinterpret_cast<const float4*>(&Bs[kk][tx*4]);
      float b_[4] = {bv4.x,bv4.y,bv4.z,bv4.w};
#pragma unroll
      for (int j=0;j<4;j++){
        acc[0][j] = fmaf(a0, b_[j], acc[0][j]);
        acc[1][j] = fmaf(a1, b_[j], acc[1][j]);
      }
    }
    __syncthreads();
  }
#pragma unroll
  for (int i=0;i<2;i++){
    const int row = bm + ty*2 + i;
#pragma unroll
    for (int j=0;j<4;j++){
      const int col = bn + tx*4 + j;
      if (col < CNCLS){
        float bias = (col < CNREL) ? fc2b[col] : fc3b[col-CNREL];
        out[(size_t)row*CNCLS + col] = acc[i][j] + bias;
      }
    }
  }
}

// ---------------- CE per row + in-place BIG mask ----------------
__global__ __launch_bounds__(256)
void k_ce(float* __restrict__ fcp, const float* __restrict__ gt,
          const int* __restrict__ mask_type, float* __restrict__ cer, float* __restrict__ cet)
{
  __shared__ float red[8];
  const int b = blockIdx.x, tid = threadIdx.x;
  float* row = fcp + (size_t)b*CNCLS;
  const float* g = gt + (size_t)b*CNCLS;
  float mx = -3.0e38f;
  for (int c=tid;c<CNREL;c+=256) mx = fmaxf(mx, row[c]);
  mx = blk_max(mx, red);
  float se=0.f, dt=0.f, gs=0.f;
  for (int c=tid;c<CNREL;c+=256){ float f=row[c], gv=g[c]; se+=expf(f-mx); dt=fmaf(gv,f,dt); gs+=gv; }
  se = blk_sum(se, red); dt = blk_sum(dt, red); gs = blk_sum(gs, red);
  if (tid==0) cer[b] = mx + logf(se) - dt/gs;
  float mx2 = -3.0e38f;
  for (int c=CNREL+tid;c<CNCLS;c+=256) mx2 = fmaxf(mx2, row[c]);
  mx2 = blk_max(mx2, red);
  float se2=0.f, dt2=0.f, gs2=0.f;
  for (int c=CNREL+tid;c<CNCLS;c+=256){ float f=row[c], gv=g[c]; se2+=expf(f-mx2); dt2=fmaf(gv,f,dt2); gs2+=gv; }
  se2 = blk_sum(se2, red); dt2 = blk_sum(dt2, red); gs2 = blk_sum(gs2, red);
  if (tid==0) cet[b] = mx2 + logf(se2) - dt2/gs2;
  __syncthreads();
  if (mask_type[b]==1){ for (int c=tid;c<CNREL;c+=256) row[c] -= BIGF; }
  else                { for (int c=CNREL+tid;c<CNCLS;c+=256) row[c] -= BIGF; }
}

__global__ __launch_bounds__(256)
void k_loss(const float* __restrict__ cer, const float* __restrict__ cet,
            const int* __restrict__ mask_type, float* __restrict__ outp)
{
  __shared__ float red[8];
  const int tid = threadIdx.x;
  float sr=0.f, st=0.f, nr=0.f, nt=0.f;
  for (int b=tid;b<CB;b+=256){
    int mt = mask_type[b];
    if (mt==-1){ sr += cer[b]; nr += 1.f; }
    else if (mt==1){ st += cet[b]; nt += 1.f; }
  }
  sr = blk_sum(sr, red); st = blk_sum(st, red);
  nr = blk_sum(nr, red); nt = blk_sum(nt, red);
  if (tid==0) outp[0] = sr/fmaxf(nr,1.f) + st/fmaxf(nt,1.f);
}

// ---------------- host orchestration ----------------
extern "C" void kernel_launch(void* const* d_in, const int* in_sizes, int n_in,
                              void* d_out, int out_size, void* d_ws, size_t ws_size,
                              hipStream_t stream)
{
  (void)in_sizes; (void)n_in; (void)out_size; (void)ws_size;
  const int*   input_ids  = (const int*)  d_in[0];
  const float* input_mask = (const float*)d_in[1];
  const int*   edge_labels= (const int*)  d_in[2];
  const int*   mask_pos   = (const int*)  d_in[3];
  const int*   mask_type  = (const int*)  d_in[5];
  const int*   ent_types  = (const int*)  d_in[6];
  const float* gtruth     = (const float*)d_in[7];
  const int*   l2m        = (const int*)  d_in[8];
  const float* emb        = (const float*)d_in[9];
  const float* ln1g=(const float*)d_in[10], *ln1b=(const float*)d_in[11];
  const float* ln2g=(const float*)d_in[12], *ln2b=(const float*)d_in[13];
  const float* fc2b=(const float*)d_in[14], *fc3b=(const float*)d_in[15];
  const float* ektab=(const float*)d_in[16], *evtab=(const float*)d_in[17];
  const float* g1W=(const float*)d_in[18], *g1as=(const float*)d_in[19], *g1ad=(const float*)d_in[20];
  const float* g2W=(const float*)d_in[21], *g2as=(const float*)d_in[22], *g2ad=(const float*)d_in[23];
  const float* wqkv=(const float*)d_in[24], *wo=(const float*)d_in[25];
  const float* el1g=(const float*)d_in[26], *el1b=(const float*)d_in[27];
  const float* w1=(const float*)d_in[28], *b1=(const float*)d_in[29];
  const float* w2=(const float*)d_in[30], *b2=(const float*)d_in[31];
  const float* el2g=(const float*)d_in[32], *el2b=(const float*)d_in[33];

  char* wsb = (char*)d_ws;
  size_t off = 0;
  auto alloc = [&](size_t bytes)->char*{
    char* p = wsb + off;
    off += (bytes + 255) & ~(size_t)255;
    return p;
  };
  int*   itt  = (int*)  alloc((size_t)NN*CSP*4);
  float* TW1  = (float*)alloc((size_t)NTAB*CD*4);
  float* Ts1  = (float*)alloc(NTAB*4);
  float* Tt1  = (float*)alloc(NTAB*4);
  float* TW2  = (float*)alloc((size_t)NTAB*CD*4);
  float* Ts2  = (float*)alloc(NTAB*4);
  float* Tt2  = (float*)alloc(NTAB*4);
  float* g1o  = (float*)alloc((size_t)NN*CD*4);     // g1; later reused as g2 output
  float* G1W  = (float*)alloc((size_t)NN*CD*4);
  float* G1s  = (float*)alloc(NN*4);
  float* G1t  = (float*)alloc(NN*4);
  float* G1rs = (float*)alloc(NN*4);
  float* xb   = (float*)alloc((size_t)NSR*CD*4);
  ushort* xhi = (ushort*)alloc((size_t)NSR*CD*2);
  ushort* xlo = (ushort*)alloc((size_t)NSR*CD*2);
  ushort* ctxhi = (ushort*)alloc((size_t)NSR*CD*2);
  ushort* ctxlo = (ushort*)alloc((size_t)NSR*CD*2);
  char*  qkvR = alloc((size_t)NSR*768*4);           // 69.2MB region, multi-aliased
  ushort* wbuf = (ushort*)alloc((size_t)12845056*2);
  float* hm   = (float*)alloc((size_t)CB*CD*4);
  float* cer  = (float*)alloc(CB*4);
  float* cet  = (float*)alloc(CB*4);

  float* qkvb = (float*)qkvR;
  // GAT-phase aliases (dead before encoder starts)
  ushort* H1hi = (ushort*)qkvR;
  ushort* H1lo = (ushort*)(qkvR + (size_t)16*1024*1024);
  float*  Zbuf = (float*)(qkvR + (size_t)32*1024*1024);
  // FFN-phase aliases (qkv dead after attn within each layer)
  ushort* ffhi = (ushort*)qkvR;
  ushort* fflo = (ushort*)(qkvR + (size_t)24*1024*1024);
  float* g2o = g1o;

  // split-weight layout within wbuf (ushort offsets)
  ushort* wqkvT = wbuf;                         // 12 * 2*768*256
  ushort* woT   = wqkvT + (size_t)12*2*768*256; // 12 * 2*256*256
  ushort* w1T   = woT   + (size_t)12*2*256*256; // 12 * 2*512*256
  ushort* w2T   = w1T   + (size_t)12*2*512*256; // 12 * 2*256*512
  ushort* g1wT  = w2T   + (size_t)12*2*256*512; // 2*256*256
  ushort* g2wT  = g1wT  + (size_t)2*256*256;

  float* dout = (float*)d_out;
  float* fcp  = dout + 1;

  // ---- weight split/transpose (6 launches) ----
  k_wsplit<<<dim3(24,8,12),dim3(256),0,stream>>>(wqkv, wqkvT, 256, 768);
  k_wsplit<<<dim3(8,8,12),dim3(256),0,stream>>>(wo, woT, 256, 256);
  k_wsplit<<<dim3(16,8,12),dim3(256),0,stream>>>(w1, w1T, 256, 512);
  k_wsplit<<<dim3(8,16,12),dim3(256),0,stream>>>(w2, w2T, 512, 256);
  k_wsplit<<<dim3(8,8,1),dim3(256),0,stream>>>(g1W + CD*CD, g1wT, 256, 256);
  k_wsplit<<<dim3(8,8,1),dim3(256),0,stream>>>(g2W + CD*CD, g2wT, 256, 256);

  // ---- GAT pipeline ----
  k_typeprep<<<dim3((NN*CSP+255)/256),dim3(256),0,stream>>>(input_ids, ent_types, itt);
  k_tables<<<dim3(NTAB),dim3(256),0,stream>>>(emb, g1W, g1as, g1ad, TW1, Ts1, Tt1);
  k_tables<<<dim3(NTAB),dim3(256),0,stream>>>(emb, g2W, g2as, g2ad, TW2, Ts2, Tt2);
  for (int c=0;c<NN/GCH;c++){
    int nb0 = c*GCH;
    k_gatl1<10><<<dim3(GCH),dim3(256),0,stream>>>(nb0, itt, TW1, Ts1, Tt1,
        nullptr,nullptr,nullptr,nullptr,nullptr, H1hi, H1lo);
    k_mgemm<0,false><<<dim3(1,GCH*10/64),dim3(256),0,stream>>>(H1hi, H1lo, g1wT, g1wT+65536,
        nullptr,nullptr,nullptr,nullptr, Zbuf, nullptr,nullptr, GCH*10, 256, 256);
    k_gatl2<10><<<dim3(GCH),dim3(256),0,stream>>>(nb0, itt, nullptr, nullptr, Zbuf,
        g1as + CD, g1ad + CD, g1o);
  }
  k_gemm128<0,false><<<dim3(2,NN/128),dim3(256),0,stream>>>(g1o, g2W, nullptr, G1W, NN, 256, 256);
  k_g1red<<<dim3(NN),dim3(256),0,stream>>>(g1o, G1W, g2as, g2ad, G1s, G1t, G1rs);
  for (int c=0;c<NN/GCH;c++){
    int nb0 = c*GCH;
    k_gatl1<15><<<dim3(GCH),dim3(256),0,stream>>>(nb0, itt, TW2, Ts2, Tt2,
        G1W, G1s, G1t, G1rs, l2m, H1hi, H1lo);
    k_mgemm<0,false><<<dim3(1,GCH*15/64),dim3(256),0,stream>>>(H1hi, H1lo, g2wT, g2wT+65536,
        nullptr,nullptr,nullptr,nullptr, Zbuf, nullptr,nullptr, GCH*15, 256, 256);
    k_gatl2<15><<<dim3(GCH),dim3(256),0,stream>>>(nb0, itt, G1rs, l2m, Zbuf,
        g2as + CD, g2ad + CD, g2o);
  }
  k_x0<<<dim3(NSR),dim3(256),0,stream>>>(input_ids, mask_pos, mask_type, emb, g2o,
      ln1g, ln1b, xb, xhi, xlo);

  // ---- encoder (12 layers) ----
  for (int l=0;l<CL;l++){
    const ushort* qh = wqkvT + (size_t)l*2*768*256; const ushort* ql = qh + 768*256;
    const ushort* oh = woT   + (size_t)l*2*256*256; const ushort* ol = oh + 256*256;
    const ushort* ah = w1T   + (size_t)l*2*512*256; const ushort* a2 = ah + 512*256;
    const ushort* bh = w2T   + (size_t)l*2*256*512; const ushort* b2l= bh + 256*512;
    k_mgemm<0,false><<<dim3(3,NSR/64),dim3(256),0,stream>>>(xhi, xlo, qh, ql,
        nullptr,nullptr,nullptr,nullptr, qkvb, nullptr,nullptr, NSR, 768, 256);
    k_attn<<<dim3(CB*CH),dim3(128),0,stream>>>(qkvb, edge_labels, ektab, evtab, input_mask,
        ctxhi, ctxlo);
    k_mgemm<2,false><<<dim3(1,NSR/64),dim3(256),0,stream>>>(ctxhi, ctxlo, oh, ol,
        nullptr, xb, el1g + (size_t)l*CD, el1b + (size_t)l*CD, xb, xhi, xlo, NSR, 256, 256);
    k_mgemm<1,true><<<dim3(2,NSR/64),dim3(256),0,stream>>>(xhi, xlo, ah, a2,
        b1 + (size_t)l*512, nullptr,nullptr,nullptr, nullptr, ffhi, fflo, NSR, 512, 256);
    k_mgemm<2,true><<<dim3(1,NSR/64),dim3(256),0,stream>>>(ffhi, fflo, bh, b2l,
        b2 + (size_t)l*CD, xb, el2g + (size_t)l*CD, el2b + (size_t)l*CD, xb, xhi, xlo, NSR, 256, 512);
  }

  // ---- head / classifier / loss ----
  k_head<<<dim3(CB),dim3(256),0,stream>>>(xb, mask_pos, ln2g, ln2b, hm);
  k_fc<<<dim3((CNCLS+63)/64, CB/32),dim3(256),0,stream>>>(hm, emb, fc2b, fc3b, fcp);
  k_ce<<<dim3(CB),dim3(256),0,stream>>>(fcp, gtruth, mask_type, cer, cet);
  k_loss<<<dim3(1),dim3(256),0,stream>>>(cer, cet, mask_type, dout);
}

// Round 4
// 3663.712 us; speedup vs baseline: 1.9995x; 1.1643x over previous
//
#include <hip/hip_runtime.h>
#include <math.h>

// ---------------- problem constants ----------------
constexpr int CB=2048, CMA=6, CS=11, CSP=10, CD=256, CH=4, CDH=64, CL=12;
constexpr int CNREL=500, CNTYPE=1000, CNODE=100000, CVOC=99000, CNCLS=1500;
constexpr int NN  = CB*CMA;     // 12288 GAT nodes
constexpr int NSR = CB*CS;      // 22528 sequence rows
constexpr int NTAB= 3+CNTYPE;   // 1003 distinct type-embedding rows
constexpr int GCH = 2048;       // GAT node chunk
constexpr float BIGF = 1000000.0f;

typedef __attribute__((ext_vector_type(8))) short short8v;
typedef __attribute__((ext_vector_type(4))) float f32x4;
typedef unsigned short ushort;

__device__ __forceinline__ float lreluf(float x){ return x>=0.f ? x : 0.2f*x; }
__device__ __forceinline__ float eluf1(float x){ return x>0.f ? x : expm1f(x); }
__device__ __forceinline__ float geluf(float x){ return 0.5f*x*(1.f+erff(x*0.70710678118654752f)); }

__device__ __forceinline__ ushort f2bf(float v){
  unsigned u = __float_as_uint(v);
  unsigned r = (u + 0x7FFFu + ((u>>16)&1u)) >> 16;
  return (ushort)r;
}
__device__ __forceinline__ float bf2f(ushort s){ return __uint_as_float(((unsigned)s)<<16); }
__device__ __forceinline__ void split2(float v, ushort& h, ushort& l){
  h = f2bf(v); l = f2bf(v - bf2f(h));
}

// block=256 reductions (4 waves)
__device__ __forceinline__ float blk_sum(float v, float* red){
#pragma unroll
  for (int o=32;o;o>>=1) v += __shfl_down(v,o,64);
  __syncthreads();
  if ((threadIdx.x&63)==0) red[threadIdx.x>>6]=v;
  __syncthreads();
  return red[0]+red[1]+red[2]+red[3];
}
__device__ __forceinline__ float blk_max(float v, float* red){
#pragma unroll
  for (int o=32;o;o>>=1) v = fmaxf(v,__shfl_down(v,o,64));
  __syncthreads();
  if ((threadIdx.x&63)==0) red[threadIdx.x>>6]=v;
  __syncthreads();
  return fmaxf(fmaxf(red[0],red[1]),fmaxf(red[2],red[3]));
}

// ---------------- weight split+transpose: f32 [K][N] -> bf16 hi/lo [N][K] ----------------
__global__ __launch_bounds__(256)
void k_wsplit(const float* __restrict__ src0, ushort* __restrict__ dst0, int K, int N)
{
  __shared__ float t[32][33];
  const int z = blockIdx.z;
  const float* src = src0 + (size_t)z*K*N;
  ushort* hi = dst0 + (size_t)z*2*K*N;
  ushort* lo = hi + (size_t)K*N;
  const int nb = blockIdx.x*32, kb = blockIdx.y*32;
  const int r = threadIdx.x>>5, c = threadIdx.x&31;
#pragma unroll
  for (int i=0;i<4;i++)
    t[r+8*i][c] = src[(size_t)(kb + r + 8*i)*N + nb + c];
  __syncthreads();
#pragma unroll
  for (int i=0;i<4;i++){
    int lin = threadIdx.x + 256*i;
    int n = lin>>5, k = lin&31;
    float v = t[k][n];
    ushort h, l; split2(v, h, l);
    hi[(size_t)(nb+n)*K + kb + k] = h;
    lo[(size_t)(nb+n)*K + kb + k] = l;
  }
}

// ---------------- bf16x3 MFMA GEMM, tile 64x256, BK=32 ----------------
template<int EPI, bool BIAS>
__global__ __launch_bounds__(256,2)
void k_mgemm(const ushort* __restrict__ Ahi, const ushort* __restrict__ Alo,
             const ushort* __restrict__ Bhi, const ushort* __restrict__ Blo,
             const float* __restrict__ bias, const float* __restrict__ res,
             const float* __restrict__ lng, const float* __restrict__ lnb,
             float* __restrict__ C, ushort* __restrict__ Chi, ushort* __restrict__ Clo,
             int M, int N, int K)
{
  constexpr int LDK = 40;
  __shared__ alignas(16) ushort Ash[2][64*LDK];
  __shared__ alignas(16) ushort Bsh[2][256*LDK];
  const int tid = threadIdx.x;
  const int wv = tid>>6, ln = tid&63;
  const int fr = ln&15, fq = ln>>4;
  const int bm = blockIdx.y*64, bn = blockIdx.x*256;
  f32x4 acc[4][4];
#pragma unroll
  for (int m=0;m<4;m++)
#pragma unroll
    for (int n=0;n<4;n++) acc[m][n] = (f32x4){0.f,0.f,0.f,0.f};

  for (int k0=0;k0<K;k0+=32){
    __syncthreads();
#pragma unroll
    for (int s=0;s<10;s++){
      int u = tid + s*256;
      const ushort* gp; ushort* lp;
      if (u < 512){
        int hl = u>>8, r = (u>>2)&63, ko = (u&3)*8;
        gp = (hl ? Alo : Ahi) + (size_t)(bm+r)*K + k0 + ko;
        lp = &Ash[hl][r*LDK + ko];
      } else {
        int u2 = u - 512;
        int hl = u2>>10, r = (u2>>2)&255, ko = (u2&3)*8;
        gp = (hl ? Blo : Bhi) + (size_t)(bn+r)*K + k0 + ko;
        lp = &Bsh[hl][r*LDK + ko];
      }
      *(short8v*)lp = *(const short8v*)gp;
    }
    __syncthreads();
    short8v ah[4], al[4], bh[4], bl[4];
#pragma unroll
    for (int m=0;m<4;m++){
      ah[m] = *(const short8v*)&Ash[0][(m*16+fr)*LDK + fq*8];
      al[m] = *(const short8v*)&Ash[1][(m*16+fr)*LDK + fq*8];
    }
#pragma unroll
    for (int n=0;n<4;n++){
      bh[n] = *(const short8v*)&Bsh[0][(wv*64+n*16+fr)*LDK + fq*8];
      bl[n] = *(const short8v*)&Bsh[1][(wv*64+n*16+fr)*LDK + fq*8];
    }
#pragma unroll
    for (int m=0;m<4;m++)
#pragma unroll
      for (int n=0;n<4;n++){
        acc[m][n] = __builtin_amdgcn_mfma_f32_16x16x32_bf16(ah[m], bh[n], acc[m][n], 0,0,0);
        acc[m][n] = __builtin_amdgcn_mfma_f32_16x16x32_bf16(ah[m], bl[n], acc[m][n], 0,0,0);
        acc[m][n] = __builtin_amdgcn_mfma_f32_16x16x32_bf16(al[m], bh[n], acc[m][n], 0,0,0);
      }
  }

  if constexpr (EPI == 0){
#pragma unroll
    for (int m=0;m<4;m++)
#pragma unroll
      for (int j=0;j<4;j++){
        size_t ro = (size_t)(bm + m*16 + fq*4 + j)*N;
#pragma unroll
        for (int n=0;n<4;n++)
          C[ro + bn + wv*64 + n*16 + fr] = acc[m][n][j];
      }
  }
  if constexpr (EPI == 1){
    float bcol[4];
#pragma unroll
    for (int n=0;n<4;n++) bcol[n] = BIAS ? bias[bn + wv*64 + n*16 + fr] : 0.f;
#pragma unroll
    for (int m=0;m<4;m++)
#pragma unroll
      for (int j=0;j<4;j++){
        size_t ro = (size_t)(bm + m*16 + fq*4 + j)*N;
#pragma unroll
        for (int n=0;n<4;n++){
          float v = geluf(acc[m][n][j] + bcol[n]);
          ushort hh,ll; split2(v,hh,ll);
          size_t o = ro + bn + wv*64 + n*16 + fr;
          Chi[o]=hh; Clo[o]=ll;
        }
      }
  }
  if constexpr (EPI == 2){
    float bcol[4], gcol[4], bbcol[4];
#pragma unroll
    for (int n=0;n<4;n++){
      int col = wv*64 + n*16 + fr;
      bcol[n] = BIAS ? bias[col] : 0.f;
      gcol[n] = lng[col]; bbcol[n] = lnb[col];
    }
    float sum_[4][4], sq_[4][4];
#pragma unroll
    for (int m=0;m<4;m++)
#pragma unroll
      for (int j=0;j<4;j++){
        size_t ro = (size_t)(bm + m*16 + fq*4 + j)*256;
        float s=0.f, q=0.f;
#pragma unroll
        for (int n=0;n<4;n++){
          float f = acc[m][n][j] + bcol[n] + res[ro + wv*64 + n*16 + fr];
          acc[m][n][j] = f; s += f; q = fmaf(f,f,q);
        }
#pragma unroll
        for (int o=1;o<16;o<<=1){ s += __shfl_xor(s,o,64); q += __shfl_xor(q,o,64); }
        sum_[m][j]=s; sq_[m][j]=q;
      }
    __syncthreads();
    float* redS = (float*)&Ash[0][0];
    if (fr==0){
#pragma unroll
      for (int m=0;m<4;m++)
#pragma unroll
        for (int j=0;j<4;j++){
          int r = m*16 + fq*4 + j;
          redS[wv*64 + r] = sum_[m][j];
          redS[256 + wv*64 + r] = sq_[m][j];
        }
    }
    __syncthreads();
#pragma unroll
    for (int m=0;m<4;m++)
#pragma unroll
      for (int j=0;j<4;j++){
        int r = m*16 + fq*4 + j;
        float S = redS[r] + redS[64+r] + redS[128+r] + redS[192+r];
        float Q = redS[256+r] + redS[320+r] + redS[384+r] + redS[448+r];
        float mean = S*(1.f/256.f);
        float var  = Q*(1.f/256.f) - mean*mean;
        float rstd = 1.f/sqrtf(var + 1e-12f);
        size_t ro = (size_t)(bm + r)*256;
#pragma unroll
        for (int n=0;n<4;n++){
          int col = wv*64 + n*16 + fr;
          float o = (acc[m][n][j] - mean)*rstd*gcol[n] + bbcol[n];
          C[ro + col] = o;
          ushort hh,ll; split2(o,hh,ll);
          Chi[ro+col]=hh; Clo[ro+col]=ll;
        }
      }
  }
}

// ---------------- type prep ----------------
__global__ __launch_bounds__(256)
void k_typeprep(const int* __restrict__ input_ids, const int* __restrict__ ent_types,
                int* __restrict__ itt)
{
  int idx = blockIdx.x*256 + threadIdx.x;
  if (idx >= NN*CSP) return;
  int n = idx / CSP, sp = idx % CSP;
  int b = n / CMA, ma = n % CMA;
  int id = input_ids[b*CS + 2*ma] - CNREL;
  itt[idx] = (id < 3) ? id : ent_types[(size_t)(id-3)*(CSP+1) + sp + 1];
}

// ---------------- distinct-row tables ----------------
__global__ __launch_bounds__(256)
void k_tables(const float* __restrict__ emb, const float* __restrict__ W,
              const float* __restrict__ asrc, const float* __restrict__ adst,
              float* __restrict__ TW, float* __restrict__ Ts, float* __restrict__ Tt)
{
  __shared__ float row[CD];
  __shared__ float red[8];
  const int r = blockIdx.x, d = threadIdx.x;
  const int nrow = (r<3) ? r : (CVOC + (r-3));
  row[d] = emb[(size_t)nrow*CD + d];
  __syncthreads();
  float acc = 0.f;
  for (int k=0;k<CD;k+=4){
    const float4 hv = *reinterpret_cast<const float4*>(&row[k]);
    acc = fmaf(hv.x, W[(size_t)(k+0)*CD+d],
          fmaf(hv.y, W[(size_t)(k+1)*CD+d],
          fmaf(hv.z, W[(size_t)(k+2)*CD+d],
          fmaf(hv.w, W[(size_t)(k+3)*CD+d], acc))));
  }
  TW[(size_t)r*CD+d] = acc;
  float s = blk_sum(acc*asrc[d], red);
  float t = blk_sum(acc*adst[d], red);
  if (d==0){ Ts[r]=s; Tt[r]=t; }
}

// ---------------- f32 128x128 GEMM (GW = g1@W) ----------------
template<int ACT, bool BIAS>
__global__ __launch_bounds__(256)
void k_gemm128(const float* __restrict__ A, const float* __restrict__ Bm,
               const float* __restrict__ bias, float* __restrict__ C,
               int M, int N, int K)
{
  __shared__ alignas(16) float As[16][132];
  __shared__ alignas(16) float Bs[16][132];
  const int tid = threadIdx.x;
  const int bn = blockIdx.x*128, bm = blockIdx.y*128;
  const int tx = tid & 15, ty = tid >> 4;
  const int ar = tid >> 1, ak = (tid & 1)*8;
  const int bk = tid >> 4, bnl = (tid & 15)*8;
  const float* Ap = A + (size_t)(bm + ar)*K + ak;
  const float* Bp = Bm + (size_t)bk*N + bn + bnl;
  float acc[8][8] = {};
  for (int k0=0; k0<K; k0+=16){
    float4 av0 = *reinterpret_cast<const float4*>(Ap + k0);
    float4 av1 = *reinterpret_cast<const float4*>(Ap + k0 + 4);
    float4 bv0 = *reinterpret_cast<const float4*>(Bp + (size_t)k0*N);
    float4 bv1 = *reinterpret_cast<const float4*>(Bp + (size_t)k0*N + 4);
    __syncthreads();
    As[ak+0][ar]=av0.x; As[ak+1][ar]=av0.y; As[ak+2][ar]=av0.z; As[ak+3][ar]=av0.w;
    As[ak+4][ar]=av1.x; As[ak+5][ar]=av1.y; As[ak+6][ar]=av1.z; As[ak+7][ar]=av1.w;
    *reinterpret_cast<float4*>(&Bs[bk][bnl])   = bv0;
    *reinterpret_cast<float4*>(&Bs[bk][bnl+4]) = bv1;
    __syncthreads();
#pragma unroll
    for (int kk=0; kk<16; kk++){
      float a_[8], b_[8];
      *reinterpret_cast<float4*>(&a_[0]) = *reinterpret_cast<const float4*>(&As[kk][ty*8]);
      *reinterpret_cast<float4*>(&a_[4]) = *reinterpret_cast<const float4*>(&As[kk][ty*8+4]);
      *reinterpret_cast<float4*>(&b_[0]) = *reinterpret_cast<const float4*>(&Bs[kk][tx*8]);
      *reinterpret_cast<float4*>(&b_[4]) = *reinterpret_cast<const float4*>(&Bs[kk][tx*8+4]);
#pragma unroll
      for (int i=0;i<8;i++)
#pragma unroll
        for (int j=0;j<8;j++) acc[i][j] = fmaf(a_[i], b_[j], acc[i][j]);
    }
  }
#pragma unroll
  for (int i=0;i<8;i++){
    const int row = bm + ty*8 + i;
    float outv[8];
#pragma unroll
    for (int j=0;j<8;j++){
      float v = acc[i][j];
      if (BIAS) v += bias[bn + tx*8 + j];
      if (ACT==1) v = geluf(v);
      outv[j] = v;
    }
    *reinterpret_cast<float4*>(C + (size_t)row*N + bn + tx*8)     = *reinterpret_cast<float4*>(&outv[0]);
    *reinterpret_cast<float4*>(C + (size_t)row*N + bn + tx*8 + 4) = *reinterpret_cast<float4*>(&outv[4]);
  }
}

// ---------------- g1 reductions ----------------
__global__ __launch_bounds__(256)
void k_g1red(const float* __restrict__ g1, const float* __restrict__ GW,
             const float* __restrict__ asrc, const float* __restrict__ adst,
             float* __restrict__ Gs, float* __restrict__ Gt, float* __restrict__ Grs)
{
  __shared__ float red[8];
  const int n = blockIdx.x, d = threadIdx.x;
  float w = GW[(size_t)n*CD + d];
  float v = g1[(size_t)n*CD + d];
  float s  = blk_sum(w*asrc[d], red);
  float t  = blk_sum(w*adst[d], red);
  float rs = blk_sum(v, red);
  if (d==0){ Gs[n]=s; Gt[n]=t; Grs[n]=rs; }
}

// ---------------- GAT masked softmax ----------------
template<int P>
__device__ __forceinline__ void gat_softmax(float (*att)[P+1], const float* sA,
                                            const float* tA, const int* sg)
{
  const int i = threadIdx.x;
  if (i < P){
    if (sg[i]){
      float si = sA[i];
      float e[P];
      float m = -3.0e38f;
#pragma unroll
      for (int j=0;j<P;j++){
        e[j] = 0.f;
        if (sg[j]){ e[j] = lreluf(si + tA[j]); m = fmaxf(m, e[j]); }
      }
      float s = 0.f;
#pragma unroll
      for (int j=0;j<P;j++){
        float w = sg[j] ? expf(e[j]-m) : 0.f;
        att[i][j] = w; s += w;
      }
      float inv = 1.f/s;
#pragma unroll
      for (int j=0;j<P;j++) att[i][j] *= inv;
    } else {
#pragma unroll
      for (int j=0;j<P;j++) att[i][j] = 0.f;
    }
  }
}

// ---------------- GAT stage A ----------------
template<int P>
__global__ __launch_bounds__(256)
void k_gatl1(int nbase, const int* __restrict__ itt,
             const float* __restrict__ TW, const float* __restrict__ Ts, const float* __restrict__ Tt,
             const float* __restrict__ GW, const float* __restrict__ Gs, const float* __restrict__ Gt,
             const float* __restrict__ Grs, const int* __restrict__ l2m,
             ushort* __restrict__ H1hi, ushort* __restrict__ H1lo)
{
  __shared__ float hW[P][CD];
  __shared__ float att[P][P+1];
  __shared__ float sA[P], tA[P];
  __shared__ int sg[P], ridx[P];
  const int n = nbase + blockIdx.x;
  const int d = threadIdx.x;
  if (d < P){
    if (d < CSP){
      int it = itt[n*CSP + d];
      int r = (it < 3) ? it : (it - (CVOC - 3));
      ridx[d]=r; sg[d]=(it>0); sA[d]=Ts[r]; tA[d]=Tt[r];
    } else {
      int ma = n % CMA;
      int m = l2m[ma*(CMA-1) + (d - CSP)];
      int nb = (n / CMA)*CMA + m;
      ridx[d]=nb; sg[d]=(Grs[nb]!=0.f); sA[d]=Gs[nb]; tA[d]=Gt[nb];
    }
  }
  __syncthreads();
#pragma unroll
  for (int i=0;i<P;i++){
    const float* src = (i<CSP) ? TW : GW;
    hW[i][d] = src[(size_t)ridx[i]*CD + d];
  }
  __syncthreads();
  gat_softmax<P>(att, sA, tA, sg);
  __syncthreads();
  float h[P];
#pragma unroll
  for (int i=0;i<P;i++) h[i]=0.f;
#pragma unroll
  for (int j=0;j<P;j++){
    float w = hW[j][d];
#pragma unroll
    for (int i=0;i<P;i++) h[i] = fmaf(att[i][j], w, h[i]);
  }
  size_t rb = ((size_t)blockIdx.x*P)*CD + d;
#pragma unroll
  for (int i=0;i<P;i++){
    float e = eluf1(h[i]);
    ushort hh,ll; split2(e,hh,ll);
    H1hi[rb + (size_t)i*CD] = hh;
    H1lo[rb + (size_t)i*CD] = ll;
  }
}

// ---------------- GAT stage B ----------------
template<int P>
__global__ __launch_bounds__(256)
void k_gatl2(int nbase, const int* __restrict__ itt, const float* __restrict__ Grs,
             const int* __restrict__ l2m, const float* __restrict__ Z,
             const float* __restrict__ as2, const float* __restrict__ ad2,
             float* __restrict__ gout)
{
  __shared__ float zb[P][CD];
  __shared__ float att[P][P+1];
  __shared__ float sA[P], tA[P];
  __shared__ int sg[P];
  const int n = nbase + blockIdx.x;
  const int d = threadIdx.x;
  size_t zrow = (size_t)blockIdx.x*P*CD;
#pragma unroll
  for (int i=0;i<P;i++) zb[i][d] = Z[zrow + (size_t)i*CD + d];
  if (d < P){
    if (d < CSP) sg[d] = (itt[n*CSP + d] > 0);
    else {
      int ma = n % CMA;
      int m = l2m[ma*(CMA-1) + (d - CSP)];
      int nb = (n / CMA)*CMA + m;
      sg[d] = (Grs[nb] != 0.f);
    }
  }
  __syncthreads();
  {
    int i = d>>4, l = d&15;
    if (i < P){
      float ps=0.f, pt=0.f;
      for (int dd=l; dd<CD; dd+=16){
        float w = zb[i][dd];
        ps = fmaf(w, as2[dd], ps);
        pt = fmaf(w, ad2[dd], pt);
      }
#pragma unroll
      for (int o=8;o;o>>=1){ ps += __shfl_down(ps,o,16); pt += __shfl_down(pt,o,16); }
      if (l==0){ sA[i]=ps; tA[i]=pt; }
    }
  }
  __syncthreads();
  gat_softmax<P>(att, sA, tA, sg);
  __syncthreads();
  float x[P];
#pragma unroll
  for (int i=0;i<P;i++) x[i]=0.f;
#pragma unroll
  for (int j=0;j<P;j++){
    float w = zb[j][d];
#pragma unroll
    for (int i=0;i<P;i++) x[i] = fmaf(att[i][j], w, x[i]);
  }
  float den=0.f;
#pragma unroll
  for (int i=0;i<P;i++) den += (float)sg[i];
  den = fmaxf(den,1.f);
  float o=0.f;
#pragma unroll
  for (int i=0;i<P;i++) if (sg[i]) o += eluf1(x[i]);
  gout[(size_t)n*CD + d] = o/den;
}

// ---------------- build x0 (+ bf16 split) ----------------
__global__ __launch_bounds__(256)
void k_x0(const int* __restrict__ input_ids, const int* __restrict__ mask_pos,
          const int* __restrict__ mask_type, const float* __restrict__ emb,
          const float* __restrict__ g2, const float* __restrict__ g,
          const float* __restrict__ bta, float* __restrict__ x,
          ushort* __restrict__ xhi, ushort* __restrict__ xlo)
{
  __shared__ float red[8];
  const int row = blockIdx.x;
  const int b = row / CS, s = row % CS;
  const int d = threadIdx.x;
  float val;
  if (s == mask_pos[b]){
    int mm = (mask_type[b]==1) ? 2 : 1;
    val = emb[(size_t)mm*CD + d];
  } else if ((s & 1) == 0){
    val = g2[(size_t)(b*CMA + (s>>1))*CD + d];
  } else {
    float v = emb[(size_t)input_ids[row]*CD + d];
    float m = blk_sum(v, red)*(1.f/CD);
    float dv = v - m;
    float var = blk_sum(dv*dv, red)*(1.f/CD);
    val = dv/sqrtf(var+1e-12f)*g[d] + bta[d];
  }
  size_t o = (size_t)row*CD + d;
  x[o] = val;
  ushort hh,ll; split2(val,hh,ll);
  xhi[o]=hh; xlo[o]=ll;
}

// ---------------- fused per-(b,h) attention: float4 LDS, padded rows, no divergence -----
__global__ __launch_bounds__(128)
void k_attn(const float* __restrict__ qkv, const int* __restrict__ elab,
            const float* __restrict__ ektab, const float* __restrict__ evtab,
            const float* __restrict__ imask, ushort* __restrict__ ctxhi,
            ushort* __restrict__ ctxlo)
{
  constexpr int LDR = CDH + 4;   // 68-float row stride: stride%32=4 -> worst 2-way (free)
  __shared__ alignas(16) float qs[CS][LDR], ks[CS][LDR], vs[CS][LDR];
  __shared__ float at[CS][CS+1];
  __shared__ int   lab[CS*CS];
  __shared__ float im[CS];
  const int bh = blockIdx.x, b = bh >> 2, h = bh & 3;
  const int tid = threadIdx.x;
  const float* qb = qkv + (size_t)b*CS*768 + h*CDH;
  // stage q/k/v: 3*11*16 = 528 float4 loads
  for (int idx=tid; idx<3*CS*16; idx+=128){
    int s = idx/(CS*16), rem = idx%(CS*16), r = rem>>4, d4 = rem&15;
    float4 v = *reinterpret_cast<const float4*>(qb + (size_t)r*768 + s*256 + d4*4);
    float* dst = (s==0) ? &qs[r][d4*4] : (s==1) ? &ks[r][d4*4] : &vs[r][d4*4];
    *reinterpret_cast<float4*>(dst) = v;
  }
  for (int idx=tid; idx<CS*CS; idx+=128) lab[idx] = elab[(size_t)b*CS*CS + idx];
  if (tid < CS) im[tid] = imask[b*CS + tid];
  __syncthreads();
  // QK^T + edge-K term, one (i,j) per lane, float4 dot loops
  if (tid < CS*CS){
    int i = tid/CS, j = tid%CS;
    int l = lab[tid];
    const float4* qi = reinterpret_cast<const float4*>(&qs[i][0]);
    const float4* kj = reinterpret_cast<const float4*>(&ks[j][0]);
    const float4* er = reinterpret_cast<const float4*>(ektab + (size_t)l*CDH);
    float accq = 0.f, acce = 0.f;
#pragma unroll
    for (int t=0;t<16;t++){
      float4 q4 = qi[t], k4 = kj[t], e4 = er[t];
      accq = fmaf(q4.x,k4.x,fmaf(q4.y,k4.y,fmaf(q4.z,k4.z,fmaf(q4.w,k4.w,accq))));
      acce = fmaf(q4.x,e4.x,fmaf(q4.y,e4.y,fmaf(q4.z,e4.z,fmaf(q4.w,e4.w,acce))));
    }
    float em = (l>0) ? 1.f : 0.f;
    float amv = BIGF*(im[i]*im[j]-1.f);
    at[i][j] = (accq + em*acce)*0.125f + amv;
  }
  __syncthreads();
  if (tid < CS){
    float m = -3.0e38f;
#pragma unroll
    for (int j=0;j<CS;j++) m = fmaxf(m, at[tid][j]);
    float e[CS]; float s = 0.f;
#pragma unroll
    for (int j=0;j<CS;j++){ e[j] = expf(at[tid][j]-m); s += e[j]; }
    float inv = 1.f/s;
#pragma unroll
    for (int j=0;j<CS;j++) at[tid][j] = e[j]*inv;
  }
  __syncthreads();
  // PV + edge-V term: (i,d4) per lane, float4 over d
  for (int idx=tid; idx<CS*16; idx+=128){
    int i = idx>>4, d4 = idx&15;
    float4 a = {0.f,0.f,0.f,0.f};
#pragma unroll
    for (int j=0;j<CS;j++){
      float w = at[i][j];
      int l = lab[i*CS+j];
      float4 v4 = *reinterpret_cast<const float4*>(&vs[j][d4*4]);
      float4 e4 = *reinterpret_cast<const float4*>(evtab + (size_t)l*CDH + d4*4);
      float em = (l>0) ? 1.f : 0.f;
      a.x = fmaf(w, fmaf(em,e4.x,v4.x), a.x);
      a.y = fmaf(w, fmaf(em,e4.y,v4.y), a.y);
      a.z = fmaf(w, fmaf(em,e4.z,v4.z), a.z);
      a.w = fmaf(w, fmaf(em,e4.w,v4.w), a.w);
    }
    size_t o = ((size_t)b*CS + i)*CD + h*CDH + d4*4;
    ushort hh0,ll0,hh1,ll1,hh2,ll2,hh3,ll3;
    split2(a.x,hh0,ll0); split2(a.y,hh1,ll1); split2(a.z,hh2,ll2); split2(a.w,hh3,ll3);
    unsigned hi01 = (unsigned)hh0 | ((unsigned)hh1<<16);
    unsigned hi23 = (unsigned)hh2 | ((unsigned)hh3<<16);
    unsigned lo01 = (unsigned)ll0 | ((unsigned)ll1<<16);
    unsigned lo23 = (unsigned)ll2 | ((unsigned)ll3<<16);
    *reinterpret_cast<uint2*>(ctxhi + o) = make_uint2(hi01, hi23);
    *reinterpret_cast<uint2*>(ctxlo + o) = make_uint2(lo01, lo23);
  }
}

// ---------------- head ----------------
__global__ __launch_bounds__(256)
void k_head(const float* __restrict__ x, const int* __restrict__ mask_pos,
            const float* __restrict__ g, const float* __restrict__ bta,
            float* __restrict__ hm)
{
  __shared__ float red[8];
  const int b = blockIdx.x, d = threadIdx.x;
  float v = geluf(x[((size_t)b*CS + mask_pos[b])*CD + d]);
  float m = blk_sum(v, red)*(1.f/CD);
  float dv = v - m;
  float var = blk_sum(dv*dv, red)*(1.f/CD);
  hm[(size_t)b*CD + d] = dv/sqrtf(var+1e-7f)*g[d] + bta[d];
}

// ---------------- classifier ----------------
__global__ __launch_bounds__(256)
void k_fc(const float* __restrict__ hm, const float* __restrict__ emb,
          const float* __restrict__ fc2b, const float* __restrict__ fc3b,
          float* __restrict__ out)
{
  __shared__ alignas(16) float As[32][36];
  __shared__ alignas(16) float Bs[32][68];
  const int bn = blockIdx.x*64, bm = blockIdx.y*32;
  const int tid = threadIdx.x;
  const int tx = tid & 15, ty = tid >> 4;
  const int ar = tid >> 3, ak = (tid & 7)*4;
  const int bnl = tid >> 2, bk8 = (tid & 3)*8;
  const int c = bn + bnl;
  const float* brow = nullptr;
  if (c < CNCLS){
    int rr = (c < CNREL) ? (3 + c) : (CVOC + (c - CNREL));
    brow = emb + (size_t)rr*CD;
  }
  float acc[2][4] = {};
  for (int k0=0;k0<CD;k0+=32){
    float4 a4 = *reinterpret_cast<const float4*>(hm + (size_t)(bm+ar)*CD + k0 + ak);
    As[ak+0][ar]=a4.x; As[ak+1][ar]=a4.y; As[ak+2][ar]=a4.z; As[ak+3][ar]=a4.w;
    float4 b0 = make_float4(0.f,0.f,0.f,0.f), b1 = make_float4(0.f,0.f,0.f,0.f);
    if (brow){
      b0 = *reinterpret_cast<const float4*>(brow + k0 + bk8);
      b1 = *reinterpret_cast<const float4*>(brow + k0 + bk8 + 4);
    }
    Bs[bk8+0][bnl]=b0.x; Bs[bk8+1][bnl]=b0.y; Bs[bk8+2][bnl]=b0.z; Bs[bk8+3][bnl]=b0.w;
    Bs[bk8+4][bnl]=b1.x; Bs[bk8+5][bnl]=b1.y; Bs[bk8+6][bnl]=b1.z; Bs[bk8+7][bnl]=b1.w;
    __syncthreads();
#pragma unroll
    for (int kk=0;kk<32;kk++){
      float a0 = As[kk][ty*2+0], a1 = As[kk][ty*2+1];
      float4 bv4 = *reinterpret_cast<const float4*>(&Bs[kk][tx*4]);
      float b_[4] = {bv4.x,bv4.y,bv4.z,bv4.w};
#pragma unroll
      for (int j=0;j<4;j++){
        acc[0][j] = fmaf(a0, b_[j], acc[0][j]);
        acc[1][j] = fmaf(a1, b_[j], acc[1][j]);
      }
    }
    __syncthreads();
  }
#pragma unroll
  for (int i=0;i<2;i++){
    const int row = bm + ty*2 + i;
#pragma unroll
    for (int j=0;j<4;j++){
      const int col = bn + tx*4 + j;
      if (col < CNCLS){
        float bias = (col < CNREL) ? fc2b[col] : fc3b[col-CNREL];
        out[(size_t)row*CNCLS + col] = acc[i][j] + bias;
      }
    }
  }
}

// ---------------- CE per row + in-place BIG mask ----------------
__global__ __launch_bounds__(256)
void k_ce(float* __restrict__ fcp, const float* __restrict__ gt,
          const int* __restrict__ mask_type, float* __restrict__ cer, float* __restrict__ cet)
{
  __shared__ float red[8];
  const int b = blockIdx.x, tid = threadIdx.x;
  float* row = fcp + (size_t)b*CNCLS;
  const float* g = gt + (size_t)b*CNCLS;
  float mx = -3.0e38f;
  for (int c=tid;c<CNREL;c+=256) mx = fmaxf(mx, row[c]);
  mx = blk_max(mx, red);
  float se=0.f, dt=0.f, gs=0.f;
  for (int c=tid;c<CNREL;c+=256){ float f=row[c], gv=g[c]; se+=expf(f-mx); dt=fmaf(gv,f,dt); gs+=gv; }
  se = blk_sum(se, red); dt = blk_sum(dt, red); gs = blk_sum(gs, red);
  if (tid==0) cer[b] = mx + logf(se) - dt/gs;
  float mx2 = -3.0e38f;
  for (int c=CNREL+tid;c<CNCLS;c+=256) mx2 = fmaxf(mx2, row[c]);
  mx2 = blk_max(mx2, red);
  float se2=0.f, dt2=0.f, gs2=0.f;
  for (int c=CNREL+tid;c<CNCLS;c+=256){ float f=row[c], gv=g[c]; se2+=expf(f-mx2); dt2=fmaf(gv,f,dt2); gs2+=gv; }
  se2 = blk_sum(se2, red); dt2 = blk_sum(dt2, red); gs2 = blk_sum(gs2, red);
  if (tid==0) cet[b] = mx2 + logf(se2) - dt2/gs2;
  __syncthreads();
  if (mask_type[b]==1){ for (int c=tid;c<CNREL;c+=256) row[c] -= BIGF; }
  else                { for (int c=CNREL+tid;c<CNCLS;c+=256) row[c] -= BIGF; }
}

__global__ __launch_bounds__(256)
void k_loss(const float* __restrict__ cer, const float* __restrict__ cet,
            const int* __restrict__ mask_type, float* __restrict__ outp)
{
  __shared__ float red[8];
  const int tid = threadIdx.x;
  float sr=0.f, st=0.f, nr=0.f, nt=0.f;
  for (int b=tid;b<CB;b+=256){
    int mt = mask_type[b];
    if (mt==-1){ sr += cer[b]; nr += 1.f; }
    else if (mt==1){ st += cet[b]; nt += 1.f; }
  }
  sr = blk_sum(sr, red); st = blk_sum(st, red);
  nr = blk_sum(nr, red); nt = blk_sum(nt, red);
  if (tid==0) outp[0] = sr/fmaxf(nr,1.f) + st/fmaxf(nt,1.f);
}

// ---------------- host orchestration ----------------
extern "C" void kernel_launch(void* const* d_in, const int* in_sizes, int n_in,
                              void* d_out, int out_size, void* d_ws, size_t ws_size,
                              hipStream_t stream)
{
  (void)in_sizes; (void)n_in; (void)out_size; (void)ws_size;
  const int*   input_ids  = (const int*)  d_in[0];
  const float* input_mask = (const float*)d_in[1];
  const int*   edge_labels= (const int*)  d_in[2];
  const int*   mask_pos   = (const int*)  d_in[3];
  const int*   mask_type  = (const int*)  d_in[5];
  const int*   ent_types  = (const int*)  d_in[6];
  const float* gtruth     = (const float*)d_in[7];
  const int*   l2m        = (const int*)  d_in[8];
  const float* emb        = (const float*)d_in[9];
  const float* ln1g=(const float*)d_in[10], *ln1b=(const float*)d_in[11];
  const float* ln2g=(const float*)d_in[12], *ln2b=(const float*)d_in[13];
  const float* fc2b=(const float*)d_in[14], *fc3b=(const float*)d_in[15];
  const float* ektab=(const float*)d_in[16], *evtab=(const float*)d_in[17];
  const float* g1W=(const float*)d_in[18], *g1as=(const float*)d_in[19], *g1ad=(const float*)d_in[20];
  const float* g2W=(const float*)d_in[21], *g2as=(const float*)d_in[22], *g2ad=(const float*)d_in[23];
  const float* wqkv=(const float*)d_in[24], *wo=(const float*)d_in[25];
  const float* el1g=(const float*)d_in[26], *el1b=(const float*)d_in[27];
  const float* w1=(const float*)d_in[28], *b1=(const float*)d_in[29];
  const float* w2=(const float*)d_in[30], *b2=(const float*)d_in[31];
  const float* el2g=(const float*)d_in[32], *el2b=(const float*)d_in[33];

  char* wsb = (char*)d_ws;
  size_t off = 0;
  auto alloc = [&](size_t bytes)->char*{
    char* p = wsb + off;
    off += (bytes + 255) & ~(size_t)255;
    return p;
  };
  int*   itt  = (int*)  alloc((size_t)NN*CSP*4);
  float* TW1  = (float*)alloc((size_t)NTAB*CD*4);
  float* Ts1  = (float*)alloc(NTAB*4);
  float* Tt1  = (float*)alloc(NTAB*4);
  float* TW2  = (float*)alloc((size_t)NTAB*CD*4);
  float* Ts2  = (float*)alloc(NTAB*4);
  float* Tt2  = (float*)alloc(NTAB*4);
  float* g1o  = (float*)alloc((size_t)NN*CD*4);
  float* G1W  = (float*)alloc((size_t)NN*CD*4);
  float* G1s  = (float*)alloc(NN*4);
  float* G1t  = (float*)alloc(NN*4);
  float* G1rs = (float*)alloc(NN*4);
  float* xb   = (float*)alloc((size_t)NSR*CD*4);
  ushort* xhi = (ushort*)alloc((size_t)NSR*CD*2);
  ushort* xlo = (ushort*)alloc((size_t)NSR*CD*2);
  ushort* ctxhi = (ushort*)alloc((size_t)NSR*CD*2);
  ushort* ctxlo = (ushort*)alloc((size_t)NSR*CD*2);
  char*  qkvR = alloc((size_t)NSR*768*4);
  ushort* wbuf = (ushort*)alloc((size_t)12845056*2);
  float* hm   = (float*)alloc((size_t)CB*CD*4);
  float* cer  = (float*)alloc(CB*4);
  float* cet  = (float*)alloc(CB*4);

  float* qkvb = (float*)qkvR;
  ushort* H1hi = (ushort*)qkvR;
  ushort* H1lo = (ushort*)(qkvR + (size_t)16*1024*1024);
  float*  Zbuf = (float*)(qkvR + (size_t)32*1024*1024);
  ushort* ffhi = (ushort*)qkvR;
  ushort* fflo = (ushort*)(qkvR + (size_t)24*1024*1024);
  float* g2o = g1o;

  ushort* wqkvT = wbuf;
  ushort* woT   = wqkvT + (size_t)12*2*768*256;
  ushort* w1T   = woT   + (size_t)12*2*256*256;
  ushort* w2T   = w1T   + (size_t)12*2*512*256;
  ushort* g1wT  = w2T   + (size_t)12*2*256*512;
  ushort* g2wT  = g1wT  + (size_t)2*256*256;

  float* dout = (float*)d_out;
  float* fcp  = dout + 1;

  // ---- weight split/transpose ----
  k_wsplit<<<dim3(24,8,12),dim3(256),0,stream>>>(wqkv, wqkvT, 256, 768);
  k_wsplit<<<dim3(8,8,12),dim3(256),0,stream>>>(wo, woT, 256, 256);
  k_wsplit<<<dim3(16,8,12),dim3(256),0,stream>>>(w1, w1T, 256, 512);
  k_wsplit<<<dim3(8,16,12),dim3(256),0,stream>>>(w2, w2T, 512, 256);
  k_wsplit<<<dim3(8,8,1),dim3(256),0,stream>>>(g1W + CD*CD, g1wT, 256, 256);
  k_wsplit<<<dim3(8,8,1),dim3(256),0,stream>>>(g2W + CD*CD, g2wT, 256, 256);

  // ---- GAT pipeline ----
  k_typeprep<<<dim3((NN*CSP+255)/256),dim3(256),0,stream>>>(input_ids, ent_types, itt);
  k_tables<<<dim3(NTAB),dim3(256),0,stream>>>(emb, g1W, g1as, g1ad, TW1, Ts1, Tt1);
  k_tables<<<dim3(NTAB),dim3(256),0,stream>>>(emb, g2W, g2as, g2ad, TW2, Ts2, Tt2);
  for (int c=0;c<NN/GCH;c++){
    int nb0 = c*GCH;
    k_gatl1<10><<<dim3(GCH),dim3(256),0,stream>>>(nb0, itt, TW1, Ts1, Tt1,
        nullptr,nullptr,nullptr,nullptr,nullptr, H1hi, H1lo);
    k_mgemm<0,false><<<dim3(1,GCH*10/64),dim3(256),0,stream>>>(H1hi, H1lo, g1wT, g1wT+65536,
        nullptr,nullptr,nullptr,nullptr, Zbuf, nullptr,nullptr, GCH*10, 256, 256);
    k_gatl2<10><<<dim3(GCH),dim3(256),0,stream>>>(nb0, itt, nullptr, nullptr, Zbuf,
        g1as + CD, g1ad + CD, g1o);
  }
  k_gemm128<0,false><<<dim3(2,NN/128),dim3(256),0,stream>>>(g1o, g2W, nullptr, G1W, NN, 256, 256);
  k_g1red<<<dim3(NN),dim3(256),0,stream>>>(g1o, G1W, g2as, g2ad, G1s, G1t, G1rs);
  for (int c=0;c<NN/GCH;c++){
    int nb0 = c*GCH;
    k_gatl1<15><<<dim3(GCH),dim3(256),0,stream>>>(nb0, itt, TW2, Ts2, Tt2,
        G1W, G1s, G1t, G1rs, l2m, H1hi, H1lo);
    k_mgemm<0,false><<<dim3(1,GCH*15/64),dim3(256),0,stream>>>(H1hi, H1lo, g2wT, g2wT+65536,
        nullptr,nullptr,nullptr,nullptr, Zbuf, nullptr,nullptr, GCH*15, 256, 256);
    k_gatl2<15><<<dim3(GCH),dim3(256),0,stream>>>(nb0, itt, G1rs, l2m, Zbuf,
        g2as + CD, g2ad + CD, g2o);
  }
  k_x0<<<dim3(NSR),dim3(256),0,stream>>>(input_ids, mask_pos, mask_type, emb, g2o,
      ln1g, ln1b, xb, xhi, xlo);

  // ---- encoder (12 layers) ----
  for (int l=0;l<CL;l++){
    const ushort* qh = wqkvT + (size_t)l*2*768*256; const ushort* ql = qh + 768*256;
    const ushort* oh = woT   + (size_t)l*2*256*256; const ushort* ol = oh + 256*256;
    const ushort* ah = w1T   + (size_t)l*2*512*256; const ushort* a2 = ah + 512*256;
    const ushort* bh = w2T   + (size_t)l*2*256*512; const ushort* b2l= bh + 256*512;
    k_mgemm<0,false><<<dim3(3,NSR/64),dim3(256),0,stream>>>(xhi, xlo, qh, ql,
        nullptr,nullptr,nullptr,nullptr, qkvb, nullptr,nullptr, NSR, 768, 256);
    k_attn<<<dim3(CB*CH),dim3(128),0,stream>>>(qkvb, edge_labels, ektab, evtab, input_mask,
        ctxhi, ctxlo);
    k_mgemm<2,false><<<dim3(1,NSR/64),dim3(256),0,stream>>>(ctxhi, ctxlo, oh, ol,
        nullptr, xb, el1g + (size_t)l*CD, el1b + (size_t)l*CD, xb, xhi, xlo, NSR, 256, 256);
    k_mgemm<1,true><<<dim3(2,NSR/64),dim3(256),0,stream>>>(xhi, xlo, ah, a2,
        b1 + (size_t)l*512, nullptr,nullptr,nullptr, nullptr, ffhi, fflo, NSR, 512, 256);
    k_mgemm<2,true><<<dim3(1,NSR/64),dim3(256),0,stream>>>(ffhi, fflo, bh, b2l,
        b2 + (size_t)l*CD, xb, el2g + (size_t)l*CD, el2b + (size_t)l*CD, xb, xhi, xlo, NSR, 256, 512);
  }

  // ---- head / classifier / loss ----
  k_head<<<dim3(CB),dim3(256),0,stream>>>(xb, mask_pos, ln2g, ln2b, hm);
  k_fc<<<dim3((CNCLS+63)/64, CB/32),dim3(256),0,stream>>>(hm, emb, fc2b, fc3b, fcp);
  k_ce<<<dim3(CB),dim3(256),0,stream>>>(fcp, gtruth, mask_type, cer, cet);
  k_loss<<<dim3(1),dim3(256),0,stream>>>(cer, cet, mask_type, dout);
}

// Round 6
// 3333.955 us; speedup vs baseline: 2.1973x; 1.0989x over previous
//
#include <hip/hip_runtime.h>
#include <math.h>

// ---------------- problem constants ----------------
constexpr int CB=2048, CMA=6, CS=11, CSP=10, CD=256, CH=4, CDH=64, CL=12;
constexpr int CNREL=500, CNTYPE=1000, CNODE=100000, CVOC=99000, CNCLS=1500;
constexpr int NN  = CB*CMA;     // 12288 GAT nodes
constexpr int NSR = CB*CS;      // 22528 sequence rows
constexpr int NTAB= 3+CNTYPE;   // 1003 distinct type-embedding rows
constexpr int GCH = 2048;       // GAT node chunk
constexpr float BIGF = 1000000.0f;

typedef __attribute__((ext_vector_type(8))) short short8v;
typedef __attribute__((ext_vector_type(4))) float f32x4;
typedef unsigned short ushort;

__device__ __forceinline__ float lreluf(float x){ return x>=0.f ? x : 0.2f*x; }
__device__ __forceinline__ float eluf1(float x){ return x>0.f ? x : expm1f(x); }
__device__ __forceinline__ float geluf(float x){ return 0.5f*x*(1.f+erff(x*0.70710678118654752f)); }

__device__ __forceinline__ ushort f2bf(float v){
  unsigned u = __float_as_uint(v);
  unsigned r = (u + 0x7FFFu + ((u>>16)&1u)) >> 16;
  return (ushort)r;
}
__device__ __forceinline__ float bf2f(ushort s){ return __uint_as_float(((unsigned)s)<<16); }
__device__ __forceinline__ void split2(float v, ushort& h, ushort& l){
  h = f2bf(v); l = f2bf(v - bf2f(h));
}

// block=256 reductions (4 waves)
__device__ __forceinline__ float blk_sum(float v, float* red){
#pragma unroll
  for (int o=32;o;o>>=1) v += __shfl_down(v,o,64);
  __syncthreads();
  if ((threadIdx.x&63)==0) red[threadIdx.x>>6]=v;
  __syncthreads();
  return red[0]+red[1]+red[2]+red[3];
}
__device__ __forceinline__ float blk_max(float v, float* red){
#pragma unroll
  for (int o=32;o;o>>=1) v = fmaxf(v,__shfl_down(v,o,64));
  __syncthreads();
  if ((threadIdx.x&63)==0) red[threadIdx.x>>6]=v;
  __syncthreads();
  return fmaxf(fmaxf(red[0],red[1]),fmaxf(red[2],red[3]));
}

// ---------------- weight split+transpose: f32 [K][N] -> bf16 hi/lo [N][K] ----------------
__global__ __launch_bounds__(256)
void k_wsplit(const float* __restrict__ src0, ushort* __restrict__ dst0, int K, int N)
{
  __shared__ float t[32][33];
  const int z = blockIdx.z;
  const float* src = src0 + (size_t)z*K*N;
  ushort* hi = dst0 + (size_t)z*2*K*N;
  ushort* lo = hi + (size_t)K*N;
  const int nb = blockIdx.x*32, kb = blockIdx.y*32;
  const int r = threadIdx.x>>5, c = threadIdx.x&31;
#pragma unroll
  for (int i=0;i<4;i++)
    t[r+8*i][c] = src[(size_t)(kb + r + 8*i)*N + nb + c];
  __syncthreads();
#pragma unroll
  for (int i=0;i<4;i++){
    int lin = threadIdx.x + 256*i;
    int n = lin>>5, k = lin&31;
    float v = t[k][n];
    ushort h, l; split2(v, h, l);
    hi[(size_t)(nb+n)*K + kb + k] = h;
    lo[(size_t)(nb+n)*K + kb + k] = l;
  }
}

// ---------------- bf16x3 MFMA GEMM, tile 64x256, BK=32 ----------------
// EPI 0: C f32. EPI 1: split(gelu(C+bias)). EPI 2: f32+split LN(C(+bias)+res).
// EPI 3: C f32 + per-row dots st_s = C.u (u=lng), st_t = C.v (v=lnb).
template<int EPI, bool BIAS>
__global__ __launch_bounds__(256,2)
void k_mgemm(const ushort* __restrict__ Ahi, const ushort* __restrict__ Alo,
             const ushort* __restrict__ Bhi, const ushort* __restrict__ Blo,
             const float* __restrict__ bias, const float* __restrict__ res,
             const float* __restrict__ lng, const float* __restrict__ lnb,
             float* __restrict__ C, ushort* __restrict__ Chi, ushort* __restrict__ Clo,
             float* __restrict__ st_s, float* __restrict__ st_t,
             int M, int N, int K)
{
  constexpr int LDK = 40;
  __shared__ alignas(16) ushort Ash[2][64*LDK];
  __shared__ alignas(16) ushort Bsh[2][256*LDK];
  const int tid = threadIdx.x;
  const int wv = tid>>6, ln = tid&63;
  const int fr = ln&15, fq = ln>>4;
  const int bm = blockIdx.y*64, bn = blockIdx.x*256;
  f32x4 acc[4][4];
#pragma unroll
  for (int m=0;m<4;m++)
#pragma unroll
    for (int n=0;n<4;n++) acc[m][n] = (f32x4){0.f,0.f,0.f,0.f};

  for (int k0=0;k0<K;k0+=32){
    __syncthreads();
#pragma unroll
    for (int s=0;s<10;s++){
      int u = tid + s*256;
      const ushort* gp; ushort* lp;
      if (u < 512){
        int hl = u>>8, r = (u>>2)&63, ko = (u&3)*8;
        gp = (hl ? Alo : Ahi) + (size_t)(bm+r)*K + k0 + ko;
        lp = &Ash[hl][r*LDK + ko];
      } else {
        int u2 = u - 512;
        int hl = u2>>10, r = (u2>>2)&255, ko = (u2&3)*8;
        gp = (hl ? Blo : Bhi) + (size_t)(bn+r)*K + k0 + ko;
        lp = &Bsh[hl][r*LDK + ko];
      }
      *(short8v*)lp = *(const short8v*)gp;
    }
    __syncthreads();
    short8v ah[4], al[4], bh[4], bl[4];
#pragma unroll
    for (int m=0;m<4;m++){
      ah[m] = *(const short8v*)&Ash[0][(m*16+fr)*LDK + fq*8];
      al[m] = *(const short8v*)&Ash[1][(m*16+fr)*LDK + fq*8];
    }
#pragma unroll
    for (int n=0;n<4;n++){
      bh[n] = *(const short8v*)&Bsh[0][(wv*64+n*16+fr)*LDK + fq*8];
      bl[n] = *(const short8v*)&Bsh[1][(wv*64+n*16+fr)*LDK + fq*8];
    }
#pragma unroll
    for (int m=0;m<4;m++)
#pragma unroll
      for (int n=0;n<4;n++){
        acc[m][n] = __builtin_amdgcn_mfma_f32_16x16x32_bf16(ah[m], bh[n], acc[m][n], 0,0,0);
        acc[m][n] = __builtin_amdgcn_mfma_f32_16x16x32_bf16(ah[m], bl[n], acc[m][n], 0,0,0);
        acc[m][n] = __builtin_amdgcn_mfma_f32_16x16x32_bf16(al[m], bh[n], acc[m][n], 0,0,0);
      }
  }

  // lane owns: row = bm + m*16 + fq*4 + j ; col = bn + wv*64 + n*16 + fr
  if constexpr (EPI == 0){
#pragma unroll
    for (int m=0;m<4;m++)
#pragma unroll
      for (int j=0;j<4;j++){
        size_t ro = (size_t)(bm + m*16 + fq*4 + j)*N;
#pragma unroll
        for (int n=0;n<4;n++)
          C[ro + bn + wv*64 + n*16 + fr] = acc[m][n][j];
      }
  }
  if constexpr (EPI == 1){
    float bcol[4];
#pragma unroll
    for (int n=0;n<4;n++) bcol[n] = BIAS ? bias[bn + wv*64 + n*16 + fr] : 0.f;
#pragma unroll
    for (int m=0;m<4;m++)
#pragma unroll
      for (int j=0;j<4;j++){
        size_t ro = (size_t)(bm + m*16 + fq*4 + j)*N;
#pragma unroll
        for (int n=0;n<4;n++){
          float v = geluf(acc[m][n][j] + bcol[n]);
          ushort hh,ll; split2(v,hh,ll);
          size_t o = ro + bn + wv*64 + n*16 + fr;
          Chi[o]=hh; Clo[o]=ll;
        }
      }
  }
  if constexpr (EPI == 2){
    float bcol[4], gcol[4], bbcol[4];
#pragma unroll
    for (int n=0;n<4;n++){
      int col = wv*64 + n*16 + fr;
      bcol[n] = BIAS ? bias[col] : 0.f;
      gcol[n] = lng[col]; bbcol[n] = lnb[col];
    }
    float sum_[4][4], sq_[4][4];
#pragma unroll
    for (int m=0;m<4;m++)
#pragma unroll
      for (int j=0;j<4;j++){
        size_t ro = (size_t)(bm + m*16 + fq*4 + j)*256;
        float s=0.f, q=0.f;
#pragma unroll
        for (int n=0;n<4;n++){
          float f = acc[m][n][j] + bcol[n] + res[ro + wv*64 + n*16 + fr];
          acc[m][n][j] = f; s += f; q = fmaf(f,f,q);
        }
#pragma unroll
        for (int o=1;o<16;o<<=1){ s += __shfl_xor(s,o,64); q += __shfl_xor(q,o,64); }
        sum_[m][j]=s; sq_[m][j]=q;
      }
    __syncthreads();
    float* redS = (float*)&Ash[0][0];
    if (fr==0){
#pragma unroll
      for (int m=0;m<4;m++)
#pragma unroll
        for (int j=0;j<4;j++){
          int r = m*16 + fq*4 + j;
          redS[wv*64 + r] = sum_[m][j];
          redS[256 + wv*64 + r] = sq_[m][j];
        }
    }
    __syncthreads();
#pragma unroll
    for (int m=0;m<4;m++)
#pragma unroll
      for (int j=0;j<4;j++){
        int r = m*16 + fq*4 + j;
        float S = redS[r] + redS[64+r] + redS[128+r] + redS[192+r];
        float Q = redS[256+r] + redS[320+r] + redS[384+r] + redS[448+r];
        float mean = S*(1.f/256.f);
        float var  = Q*(1.f/256.f) - mean*mean;
        float rstd = 1.f/sqrtf(var + 1e-12f);
        size_t ro = (size_t)(bm + r)*256;
#pragma unroll
        for (int n=0;n<4;n++){
          int col = wv*64 + n*16 + fr;
          float o = (acc[m][n][j] - mean)*rstd*gcol[n] + bbcol[n];
          C[ro + col] = o;
          ushort hh,ll; split2(o,hh,ll);
          Chi[ro+col]=hh; Clo[ro+col]=ll;
        }
      }
  }
  if constexpr (EPI == 3){
    // f32 C + per-row dot products with u (lng) and v (lnb); N must be 256, grid.x==1
    float ucol[4], vcol[4];
#pragma unroll
    for (int n=0;n<4;n++){
      int col = wv*64 + n*16 + fr;
      ucol[n] = lng[col]; vcol[n] = lnb[col];
    }
    float su[4][4], sv[4][4];
#pragma unroll
    for (int m=0;m<4;m++)
#pragma unroll
      for (int j=0;j<4;j++){
        size_t ro = (size_t)(bm + m*16 + fq*4 + j)*256;
        float s=0.f, q=0.f;
#pragma unroll
        for (int n=0;n<4;n++){
          float f = acc[m][n][j];
          C[ro + wv*64 + n*16 + fr] = f;
          s = fmaf(f, ucol[n], s); q = fmaf(f, vcol[n], q);
        }
#pragma unroll
        for (int o=1;o<16;o<<=1){ s += __shfl_xor(s,o,64); q += __shfl_xor(q,o,64); }
        su[m][j]=s; sv[m][j]=q;
      }
    __syncthreads();
    float* redS = (float*)&Ash[0][0];
    if (fr==0){
#pragma unroll
      for (int m=0;m<4;m++)
#pragma unroll
        for (int j=0;j<4;j++){
          int r = m*16 + fq*4 + j;
          redS[wv*64 + r] = su[m][j];
          redS[256 + wv*64 + r] = sv[m][j];
        }
    }
    __syncthreads();
    if (wv==0 && fr==0){
#pragma unroll
      for (int m=0;m<4;m++)
#pragma unroll
        for (int j=0;j<4;j++){
          int r = m*16 + fq*4 + j;
          st_s[bm+r] = redS[r] + redS[64+r] + redS[128+r] + redS[192+r];
          st_t[bm+r] = redS[256+r] + redS[320+r] + redS[384+r] + redS[448+r];
        }
    }
  }
}

// ---------------- type prep ----------------
__global__ __launch_bounds__(256)
void k_typeprep(const int* __restrict__ input_ids, const int* __restrict__ ent_types,
                int* __restrict__ itt)
{
  int idx = blockIdx.x*256 + threadIdx.x;
  if (idx >= NN*CSP) return;
  int n = idx / CSP, sp = idx % CSP;
  int b = n / CMA, ma = n % CMA;
  int id = input_ids[b*CS + 2*ma] - CNREL;
  itt[idx] = (id < 3) ? id : ent_types[(size_t)(id-3)*(CSP+1) + sp + 1];
}

// ---------------- distinct-row tables ----------------
__global__ __launch_bounds__(256)
void k_tables(const float* __restrict__ emb, const float* __restrict__ W,
              const float* __restrict__ asrc, const float* __restrict__ adst,
              float* __restrict__ TW, float* __restrict__ Ts, float* __restrict__ Tt)
{
  __shared__ float row[CD];
  __shared__ float red[8];
  const int r = blockIdx.x, d = threadIdx.x;
  const int nrow = (r<3) ? r : (CVOC + (r-3));
  row[d] = emb[(size_t)nrow*CD + d];
  __syncthreads();
  float acc = 0.f;
  for (int k=0;k<CD;k+=4){
    const float4 hv = *reinterpret_cast<const float4*>(&row[k]);
    acc = fmaf(hv.x, W[(size_t)(k+0)*CD+d],
          fmaf(hv.y, W[(size_t)(k+1)*CD+d],
          fmaf(hv.z, W[(size_t)(k+2)*CD+d],
          fmaf(hv.w, W[(size_t)(k+3)*CD+d], acc))));
  }
  TW[(size_t)r*CD+d] = acc;
  float s = blk_sum(acc*asrc[d], red);
  float t = blk_sum(acc*adst[d], red);
  if (d==0){ Ts[r]=s; Tt[r]=t; }
}

// ---------------- wave-per-node GAT stage A: softmax1 + h1=elu(att@hW) -> bf16 splits ---
// One node per wave, 4 nodes/block. No LDS, no barriers.
template<int P>
__global__ __launch_bounds__(256,4)
void k_gatw1(int nbase, const int* __restrict__ itt,
             const float* __restrict__ TW, const float* __restrict__ Ts, const float* __restrict__ Tt,
             const float* __restrict__ GW, const float* __restrict__ Gs, const float* __restrict__ Gt,
             const float* __restrict__ Grs, const int* __restrict__ l2m,
             ushort* __restrict__ H1hi, ushort* __restrict__ H1lo)
{
  const int wv = threadIdx.x>>6, l = threadIdx.x&63;
  const int nrel = blockIdx.x*4 + wv;
  const int n = nbase + nrel;
  const int j = l & 15;
  int ridx=0, sg=0; float sv=0.f, tv=0.f;
  if (j < P){
    if (j < CSP){
      int it = itt[n*CSP + j];
      int r = (it<3) ? it : (it-(CVOC-3));
      ridx=r; sg=(it>0); sv=Ts[r]; tv=Tt[r];
    } else {
      int ma = n % CMA;
      int m = l2m[ma*(CMA-1) + (j-CSP)];
      int nb = (n/CMA)*CMA + m;
      ridx=nb; sg=(Grs[nb]!=0.f); sv=Gs[nb]; tv=Gt[nb];
    }
  }
  // neighbor rows -> registers (cols 4l..4l+3)
  float4 z[P];
#pragma unroll
  for (int i=0;i<P;i++){
    int ri = __shfl(ridx, i);
    const float* src = (i<CSP) ? TW : GW;
    z[i] = *reinterpret_cast<const float4*>(src + (size_t)ri*CD + 4*l);
  }
  // att[i][j] on lane j (replicated across 16-lane groups)
  float att[P];
#pragma unroll
  for (int i=0;i<P;i++){
    float si = __shfl(sv, i);
    int  sgi = __shfl(sg, i);
    int act = sgi && sg && (j<P);
    float e = act ? lreluf(si+tv) : -3.0e38f;
    float m = e;
#pragma unroll
    for (int o=1;o<16;o<<=1) m = fmaxf(m, __shfl_xor(m,o,16));
    float w = act ? expf(e-m) : 0.f;
    float s = w;
#pragma unroll
    for (int o=1;o<16;o<<=1) s += __shfl_xor(s,o,16);
    att[i] = sgi ? w*(1.f/s) : 0.f;
  }
  // x[i] = att[i] @ z ; elu; split; store
  size_t rb = ((size_t)nrel*P)*CD + 4*l;
#pragma unroll
  for (int i=0;i<P;i++){
    float4 x = {0.f,0.f,0.f,0.f};
#pragma unroll
    for (int jj=0;jj<P;jj++){
      float a = __shfl(att[i], jj);
      x.x = fmaf(a, z[jj].x, x.x);
      x.y = fmaf(a, z[jj].y, x.y);
      x.z = fmaf(a, z[jj].z, x.z);
      x.w = fmaf(a, z[jj].w, x.w);
    }
    float e0=eluf1(x.x), e1=eluf1(x.y), e2=eluf1(x.z), e3=eluf1(x.w);
    ushort h0,l0,h1,l1,h2,l2,h3,l3;
    split2(e0,h0,l0); split2(e1,h1,l1); split2(e2,h2,l2); split2(e3,h3,l3);
    size_t o = rb + (size_t)i*CD;
    *reinterpret_cast<uint2*>(H1hi + o) = make_uint2((unsigned)h0|((unsigned)h1<<16), (unsigned)h2|((unsigned)h3<<16));
    *reinterpret_cast<uint2*>(H1lo + o) = make_uint2((unsigned)l0|((unsigned)l1<<16), (unsigned)l2|((unsigned)l3<<16));
  }
}

// ---------------- wave-per-node GAT stage B: softmax2 + masked mean of elu(att@Z) -------
template<int P, bool SPLIT, bool WRS>
__global__ __launch_bounds__(256,4)
void k_gatw2(int nbase, const int* __restrict__ itt, const float* __restrict__ Grs_in,
             const int* __restrict__ l2m, const float* __restrict__ Z,
             const float* __restrict__ Zs, const float* __restrict__ Zt,
             float* __restrict__ gout, ushort* __restrict__ ghi, ushort* __restrict__ glo,
             float* __restrict__ Grs_out)
{
  const int wv = threadIdx.x>>6, l = threadIdx.x&63;
  const int nrel = blockIdx.x*4 + wv;
  const int n = nbase + nrel;
  const int j = l & 15;
  int sg=0; float sv=0.f, tv=0.f;
  if (j < P){
    if (j < CSP) sg = (itt[n*CSP + j] > 0);
    else {
      int ma = n % CMA;
      int m = l2m[ma*(CMA-1) + (j-CSP)];
      int nb = (n/CMA)*CMA + m;
      sg = (Grs_in[nb] != 0.f);
    }
    sv = Zs[nrel*P + j]; tv = Zt[nrel*P + j];
  }
  float4 z[P];
#pragma unroll
  for (int i=0;i<P;i++)
    z[i] = *reinterpret_cast<const float4*>(Z + ((size_t)nrel*P + i)*CD + 4*l);
  float att[P];
#pragma unroll
  for (int i=0;i<P;i++){
    float si = __shfl(sv, i);
    int  sgi = __shfl(sg, i);
    int act = sgi && sg && (j<P);
    float e = act ? lreluf(si+tv) : -3.0e38f;
    float m = e;
#pragma unroll
    for (int o=1;o<16;o<<=1) m = fmaxf(m, __shfl_xor(m,o,16));
    float w = act ? expf(e-m) : 0.f;
    float s = w;
#pragma unroll
    for (int o=1;o<16;o<<=1) s += __shfl_xor(s,o,16);
    att[i] = sgi ? w*(1.f/s) : 0.f;
  }
  float den = (j<P) ? (float)sg : 0.f;
#pragma unroll
  for (int o=1;o<16;o<<=1) den += __shfl_xor(den,o,16);
  den = fmaxf(den, 1.f);
  float4 acc = {0.f,0.f,0.f,0.f};
#pragma unroll
  for (int i=0;i<P;i++){
    float4 x = {0.f,0.f,0.f,0.f};
#pragma unroll
    for (int jj=0;jj<P;jj++){
      float a = __shfl(att[i], jj);
      x.x = fmaf(a, z[jj].x, x.x);
      x.y = fmaf(a, z[jj].y, x.y);
      x.z = fmaf(a, z[jj].z, x.z);
      x.w = fmaf(a, z[jj].w, x.w);
    }
    int sgi = __shfl(sg, i);
    if (sgi){
      acc.x += eluf1(x.x); acc.y += eluf1(x.y);
      acc.z += eluf1(x.z); acc.w += eluf1(x.w);
    }
  }
  float inv = 1.f/den;
  acc.x *= inv; acc.y *= inv; acc.z *= inv; acc.w *= inv;
  *reinterpret_cast<float4*>(gout + (size_t)n*CD + 4*l) = acc;
  if constexpr (SPLIT){
    ushort h0,l0,h1,l1,h2,l2,h3,l3;
    split2(acc.x,h0,l0); split2(acc.y,h1,l1); split2(acc.z,h2,l2); split2(acc.w,h3,l3);
    size_t o = (size_t)n*CD + 4*l;
    *reinterpret_cast<uint2*>(ghi + o) = make_uint2((unsigned)h0|((unsigned)h1<<16), (unsigned)h2|((unsigned)h3<<16));
    *reinterpret_cast<uint2*>(glo + o) = make_uint2((unsigned)l0|((unsigned)l1<<16), (unsigned)l2|((unsigned)l3<<16));
  }
  if constexpr (WRS){
    float tot = acc.x + acc.y + acc.z + acc.w;
#pragma unroll
    for (int o=1;o<64;o<<=1) tot += __shfl_xor(tot,o,64);
    if (l==0) Grs_out[n] = tot;
  }
}

// ---------------- build x0 (+ bf16 split) ----------------
__global__ __launch_bounds__(256)
void k_x0(const int* __restrict__ input_ids, const int* __restrict__ mask_pos,
          const int* __restrict__ mask_type, const float* __restrict__ emb,
          const float* __restrict__ g2, const float* __restrict__ g,
          const float* __restrict__ bta, float* __restrict__ x,
          ushort* __restrict__ xhi, ushort* __restrict__ xlo)
{
  __shared__ float red[8];
  const int row = blockIdx.x;
  const int b = row / CS, s = row % CS;
  const int d = threadIdx.x;
  float val;
  if (s == mask_pos[b]){
    int mm = (mask_type[b]==1) ? 2 : 1;
    val = emb[(size_t)mm*CD + d];
  } else if ((s & 1) == 0){
    val = g2[(size_t)(b*CMA + (s>>1))*CD + d];
  } else {
    float v = emb[(size_t)input_ids[row]*CD + d];
    float m = blk_sum(v, red)*(1.f/CD);
    float dv = v - m;
    float var = blk_sum(dv*dv, red)*(1.f/CD);
    val = dv/sqrtf(var+1e-12f)*g[d] + bta[d];
  }
  size_t o = (size_t)row*CD + d;
  x[o] = val;
  ushort hh,ll; split2(val,hh,ll);
  xhi[o]=hh; xlo[o]=ll;
}

// ---------------- fused per-(b,h) attention: float4 LDS, padded rows ----------------
__global__ __launch_bounds__(128)
void k_attn(const float* __restrict__ qkv, const int* __restrict__ elab,
            const float* __restrict__ ektab, const float* __restrict__ evtab,
            const float* __restrict__ imask, ushort* __restrict__ ctxhi,
            ushort* __restrict__ ctxlo)
{
  constexpr int LDR = CDH + 4;
  __shared__ alignas(16) float qs[CS][LDR], ks[CS][LDR], vs[CS][LDR];
  __shared__ float at[CS][CS+1];
  __shared__ int   lab[CS*CS];
  __shared__ float im[CS];
  const int bh = blockIdx.x, b = bh >> 2, h = bh & 3;
  const int tid = threadIdx.x;
  const float* qb = qkv + (size_t)b*CS*768 + h*CDH;
  for (int idx=tid; idx<3*CS*16; idx+=128){
    int s = idx/(CS*16), rem = idx%(CS*16), r = rem>>4, d4 = rem&15;
    float4 v = *reinterpret_cast<const float4*>(qb + (size_t)r*768 + s*256 + d4*4);
    float* dst = (s==0) ? &qs[r][d4*4] : (s==1) ? &ks[r][d4*4] : &vs[r][d4*4];
    *reinterpret_cast<float4*>(dst) = v;
  }
  for (int idx=tid; idx<CS*CS; idx+=128) lab[idx] = elab[(size_t)b*CS*CS + idx];
  if (tid < CS) im[tid] = imask[b*CS + tid];
  __syncthreads();
  if (tid < CS*CS){
    int i = tid/CS, j = tid%CS;
    int l = lab[tid];
    const float4* qi = reinterpret_cast<const float4*>(&qs[i][0]);
    const float4* kj = reinterpret_cast<const float4*>(&ks[j][0]);
    const float4* er = reinterpret_cast<const float4*>(ektab + (size_t)l*CDH);
    float accq = 0.f, acce = 0.f;
#pragma unroll
    for (int t=0;t<16;t++){
      float4 q4 = qi[t], k4 = kj[t], e4 = er[t];
      accq = fmaf(q4.x,k4.x,fmaf(q4.y,k4.y,fmaf(q4.z,k4.z,fmaf(q4.w,k4.w,accq))));
      acce = fmaf(q4.x,e4.x,fmaf(q4.y,e4.y,fmaf(q4.z,e4.z,fmaf(q4.w,e4.w,acce))));
    }
    float em = (l>0) ? 1.f : 0.f;
    float amv = BIGF*(im[i]*im[j]-1.f);
    at[i][j] = (accq + em*acce)*0.125f + amv;
  }
  __syncthreads();
  if (tid < CS){
    float m = -3.0e38f;
#pragma unroll
    for (int j=0;j<CS;j++) m = fmaxf(m, at[tid][j]);
    float e[CS]; float s = 0.f;
#pragma unroll
    for (int j=0;j<CS;j++){ e[j] = expf(at[tid][j]-m); s += e[j]; }
    float inv = 1.f/s;
#pragma unroll
    for (int j=0;j<CS;j++) at[tid][j] = e[j]*inv;
  }
  __syncthreads();
  for (int idx=tid; idx<CS*16; idx+=128){
    int i = idx>>4, d4 = idx&15;
    float4 a = {0.f,0.f,0.f,0.f};
#pragma unroll
    for (int j=0;j<CS;j++){
      float w = at[i][j];
      int l = lab[i*CS+j];
      float4 v4 = *reinterpret_cast<const float4*>(&vs[j][d4*4]);
      float4 e4 = *reinterpret_cast<const float4*>(evtab + (size_t)l*CDH + d4*4);
      float em = (l>0) ? 1.f : 0.f;
      a.x = fmaf(w, fmaf(em,e4.x,v4.x), a.x);
      a.y = fmaf(w, fmaf(em,e4.y,v4.y), a.y);
      a.z = fmaf(w, fmaf(em,e4.z,v4.z), a.z);
      a.w = fmaf(w, fmaf(em,e4.w,v4.w), a.w);
    }
    size_t o = ((size_t)b*CS + i)*CD + h*CDH + d4*4;
    ushort hh0,ll0,hh1,ll1,hh2,ll2,hh3,ll3;
    split2(a.x,hh0,ll0); split2(a.y,hh1,ll1); split2(a.z,hh2,ll2); split2(a.w,hh3,ll3);
    *reinterpret_cast<uint2*>(ctxhi + o) = make_uint2((unsigned)hh0|((unsigned)hh1<<16), (unsigned)hh2|((unsigned)hh3<<16));
    *reinterpret_cast<uint2*>(ctxlo + o) = make_uint2((unsigned)ll0|((unsigned)ll1<<16), (unsigned)ll2|((unsigned)ll3<<16));
  }
}

// ---------------- head ----------------
__global__ __launch_bounds__(256)
void k_head(const float* __restrict__ x, const int* __restrict__ mask_pos,
            const float* __restrict__ g, const float* __restrict__ bta,
            float* __restrict__ hm)
{
  __shared__ float red[8];
  const int b = blockIdx.x, d = threadIdx.x;
  float v = geluf(x[((size_t)b*CS + mask_pos[b])*CD + d]);
  float m = blk_sum(v, red)*(1.f/CD);
  float dv = v - m;
  float var = blk_sum(dv*dv, red)*(1.f/CD);
  hm[(size_t)b*CD + d] = dv/sqrtf(var+1e-7f)*g[d] + bta[d];
}

// ---------------- classifier ----------------
__global__ __launch_bounds__(256)
void k_fc(const float* __restrict__ hm, const float* __restrict__ emb,
          const float* __restrict__ fc2b, const float* __restrict__ fc3b,
          float* __restrict__ out)
{
  __shared__ alignas(16) float As[32][36];
  __shared__ alignas(16) float Bs[32][68];
  const int bn = blockIdx.x*64, bm = blockIdx.y*32;
  const int tid = threadIdx.x;
  const int tx = tid & 15, ty = tid >> 4;
  const int ar = tid >> 3, ak = (tid & 7)*4;
  const int bnl = tid >> 2, bk8 = (tid & 3)*8;
  const int c = bn + bnl;
  const float* brow = nullptr;
  if (c < CNCLS){
    int rr = (c < CNREL) ? (3 + c) : (CVOC + (c - CNREL));
    brow = emb + (size_t)rr*CD;
  }
  float acc[2][4] = {};
  for (int k0=0;k0<CD;k0+=32){
    float4 a4 = *reinterpret_cast<const float4*>(hm + (size_t)(bm+ar)*CD + k0 + ak);
    As[ak+0][ar]=a4.x; As[ak+1][ar]=a4.y; As[ak+2][ar]=a4.z; As[ak+3][ar]=a4.w;
    float4 b0 = make_float4(0.f,0.f,0.f,0.f), b1 = make_float4(0.f,0.f,0.f,0.f);
    if (brow){
      b0 = *reinterpret_cast<const float4*>(brow + k0 + bk8);
      b1 = *reinterpret_cast<const float4*>(brow + k0 + bk8 + 4);
    }
    Bs[bk8+0][bnl]=b0.x; Bs[bk8+1][bnl]=b0.y; Bs[bk8+2][bnl]=b0.z; Bs[bk8+3][bnl]=b0.w;
    Bs[bk8+4][bnl]=b1.x; Bs[bk8+5][bnl]=b1.y; Bs[bk8+6][bnl]=b1.z; Bs[bk8+7][bnl]=b1.w;
    __syncthreads();
#pragma unroll
    for (int kk=0;kk<32;kk++){
      float a0 = As[kk][ty*2+0], a1 = As[kk][ty*2+1];
      float4 bv4 = *reinterpret_cast<const float4*>(&Bs[kk][tx*4]);
      float b_[4] = {bv4.x,bv4.y,bv4.z,bv4.w};
#pragma unroll
      for (int j=0;j<4;j++){
        acc[0][j] = fmaf(a0, b_[j], acc[0][j]);
        acc[1][j] = fmaf(a1, b_[j], acc[1][j]);
      }
    }
    __syncthreads();
  }
#pragma unroll
  for (int i=0;i<2;i++){
    const int row = bm + ty*2 + i;
#pragma unroll
    for (int j=0;j<4;j++){
      const int col = bn + tx*4 + j;
      if (col < CNCLS){
        float bias = (col < CNREL) ? fc2b[col] : fc3b[col-CNREL];
        out[(size_t)row*CNCLS + col] = acc[i][j] + bias;
      }
    }
  }
}

// ---------------- CE per row + in-place BIG mask ----------------
__global__ __launch_bounds__(256)
void k_ce(float* __restrict__ fcp, const float* __restrict__ gt,
          const int* __restrict__ mask_type, float* __restrict__ cer, float* __restrict__ cet)
{
  __shared__ float red[8];
  const int b = blockIdx.x, tid = threadIdx.x;
  float* row = fcp + (size_t)b*CNCLS;
  const float* g = gt + (size_t)b*CNCLS;
  float mx = -3.0e38f;
  for (int c=tid;c<CNREL;c+=256) mx = fmaxf(mx, row[c]);
  mx = blk_max(mx, red);
  float se=0.f, dt=0.f, gs=0.f;
  for (int c=tid;c<CNREL;c+=256){ float f=row[c], gv=g[c]; se+=expf(f-mx); dt=fmaf(gv,f,dt); gs+=gv; }
  se = blk_sum(se, red); dt = blk_sum(dt, red); gs = blk_sum(gs, red);
  if (tid==0) cer[b] = mx + logf(se) - dt/gs;
  float mx2 = -3.0e38f;
  for (int c=CNREL+tid;c<CNCLS;c+=256) mx2 = fmaxf(mx2, row[c]);
  mx2 = blk_max(mx2, red);
  float se2=0.f, dt2=0.f, gs2=0.f;
  for (int c=CNREL+tid;c<CNCLS;c+=256){ float f=row[c], gv=g[c]; se2+=expf(f-mx2); dt2=fmaf(gv,f,dt2); gs2+=gv; }
  se2 = blk_sum(se2, red); dt2 = blk_sum(dt2, red); gs2 = blk_sum(gs2, red);
  if (tid==0) cet[b] = mx2 + logf(se2) - dt2/gs2;
  __syncthreads();
  if (mask_type[b]==1){ for (int c=tid;c<CNREL;c+=256) row[c] -= BIGF; }
  else                { for (int c=CNREL+tid;c<CNCLS;c+=256) row[c] -= BIGF; }
}

__global__ __launch_bounds__(256)
void k_loss(const float* __restrict__ cer, const float* __restrict__ cet,
            const int* __restrict__ mask_type, float* __restrict__ outp)
{
  __shared__ float red[8];
  const int tid = threadIdx.x;
  float sr=0.f, st=0.f, nr=0.f, nt=0.f;
  for (int b=tid;b<CB;b+=256){
    int mt = mask_type[b];
    if (mt==-1){ sr += cer[b]; nr += 1.f; }
    else if (mt==1){ st += cet[b]; nt += 1.f; }
  }
  sr = blk_sum(sr, red); st = blk_sum(st, red);
  nr = blk_sum(nr, red); nt = blk_sum(nt, red);
  if (tid==0) outp[0] = sr/fmaxf(nr,1.f) + st/fmaxf(nt,1.f);
}

// ---------------- host orchestration ----------------
extern "C" void kernel_launch(void* const* d_in, const int* in_sizes, int n_in,
                              void* d_out, int out_size, void* d_ws, size_t ws_size,
                              hipStream_t stream)
{
  (void)in_sizes; (void)n_in; (void)out_size; (void)ws_size;
  const int*   input_ids  = (const int*)  d_in[0];
  const float* input_mask = (const float*)d_in[1];
  const int*   edge_labels= (const int*)  d_in[2];
  const int*   mask_pos   = (const int*)  d_in[3];
  const int*   mask_type  = (const int*)  d_in[5];
  const int*   ent_types  = (const int*)  d_in[6];
  const float* gtruth     = (const float*)d_in[7];
  const int*   l2m        = (const int*)  d_in[8];
  const float* emb        = (const float*)d_in[9];
  const float* ln1g=(const float*)d_in[10], *ln1b=(const float*)d_in[11];
  const float* ln2g=(const float*)d_in[12], *ln2b=(const float*)d_in[13];
  const float* fc2b=(const float*)d_in[14], *fc3b=(const float*)d_in[15];
  const float* ektab=(const float*)d_in[16], *evtab=(const float*)d_in[17];
  const float* g1W=(const float*)d_in[18], *g1as=(const float*)d_in[19], *g1ad=(const float*)d_in[20];
  const float* g2W=(const float*)d_in[21], *g2as=(const float*)d_in[22], *g2ad=(const float*)d_in[23];
  const float* wqkv=(const float*)d_in[24], *wo=(const float*)d_in[25];
  const float* el1g=(const float*)d_in[26], *el1b=(const float*)d_in[27];
  const float* w1=(const float*)d_in[28], *b1=(const float*)d_in[29];
  const float* w2=(const float*)d_in[30], *b2=(const float*)d_in[31];
  const float* el2g=(const float*)d_in[32], *el2b=(const float*)d_in[33];

  char* wsb = (char*)d_ws;
  size_t off = 0;
  auto alloc = [&](size_t bytes)->char*{
    char* p = wsb + off;
    off += (bytes + 255) & ~(size_t)255;
    return p;
  };
  int*   itt  = (int*)  alloc((size_t)NN*CSP*4);
  float* TW1  = (float*)alloc((size_t)NTAB*CD*4);
  float* Ts1  = (float*)alloc(NTAB*4);
  float* Tt1  = (float*)alloc(NTAB*4);
  float* TW2  = (float*)alloc((size_t)NTAB*CD*4);
  float* Ts2  = (float*)alloc(NTAB*4);
  float* Tt2  = (float*)alloc(NTAB*4);
  float* g1o  = (float*)alloc((size_t)NN*CD*4);
  float* G1W  = (float*)alloc((size_t)NN*CD*4);
  float* G1s  = (float*)alloc(NN*4);
  float* G1t  = (float*)alloc(NN*4);
  float* G1rs = (float*)alloc(NN*4);
  ushort* g1hi = (ushort*)alloc((size_t)NN*CD*2);
  ushort* g1lo = (ushort*)alloc((size_t)NN*CD*2);
  float* Zs   = (float*)alloc((size_t)GCH*15*4);
  float* Zt   = (float*)alloc((size_t)GCH*15*4);
  float* xb   = (float*)alloc((size_t)NSR*CD*4);
  ushort* xhi = (ushort*)alloc((size_t)NSR*CD*2);
  ushort* xlo = (ushort*)alloc((size_t)NSR*CD*2);
  ushort* ctxhi = (ushort*)alloc((size_t)NSR*CD*2);
  ushort* ctxlo = (ushort*)alloc((size_t)NSR*CD*2);
  char*  qkvR = alloc((size_t)NSR*768*4);
  ushort* wbuf = (ushort*)alloc((size_t)12976128*2);
  float* hm   = (float*)alloc((size_t)CB*CD*4);
  float* cer  = (float*)alloc(CB*4);
  float* cet  = (float*)alloc(CB*4);

  float* qkvb = (float*)qkvR;
  ushort* H1hi = (ushort*)qkvR;
  ushort* H1lo = (ushort*)(qkvR + (size_t)16*1024*1024);
  float*  Zbuf = (float*)(qkvR + (size_t)32*1024*1024);
  ushort* ffhi = (ushort*)qkvR;
  ushort* fflo = (ushort*)(qkvR + (size_t)24*1024*1024);
  float* g2o = g1o;

  ushort* wqkvT = wbuf;
  ushort* woT   = wqkvT + (size_t)12*2*768*256;
  ushort* w1T   = woT   + (size_t)12*2*256*256;
  ushort* w2T   = w1T   + (size_t)12*2*512*256;
  ushort* g1wT  = w2T   + (size_t)12*2*256*512;
  ushort* g2wT  = g1wT  + (size_t)2*256*256;
  ushort* g2w0T = g2wT  + (size_t)2*256*256;

  float* dout = (float*)d_out;
  float* fcp  = dout + 1;

  // ---- weight split/transpose ----
  k_wsplit<<<dim3(24,8,12),dim3(256),0,stream>>>(wqkv, wqkvT, 256, 768);
  k_wsplit<<<dim3(8,8,12),dim3(256),0,stream>>>(wo, woT, 256, 256);
  k_wsplit<<<dim3(16,8,12),dim3(256),0,stream>>>(w1, w1T, 256, 512);
  k_wsplit<<<dim3(8,16,12),dim3(256),0,stream>>>(w2, w2T, 512, 256);
  k_wsplit<<<dim3(8,8,1),dim3(256),0,stream>>>(g1W + CD*CD, g1wT, 256, 256);
  k_wsplit<<<dim3(8,8,1),dim3(256),0,stream>>>(g2W + CD*CD, g2wT, 256, 256);
  k_wsplit<<<dim3(8,8,1),dim3(256),0,stream>>>(g2W, g2w0T, 256, 256);

  // ---- GAT pipeline ----
  k_typeprep<<<dim3((NN*CSP+255)/256),dim3(256),0,stream>>>(input_ids, ent_types, itt);
  k_tables<<<dim3(NTAB),dim3(256),0,stream>>>(emb, g1W, g1as, g1ad, TW1, Ts1, Tt1);
  k_tables<<<dim3(NTAB),dim3(256),0,stream>>>(emb, g2W, g2as, g2ad, TW2, Ts2, Tt2);
  for (int c=0;c<NN/GCH;c++){
    int nb0 = c*GCH;
    k_gatw1<10><<<dim3(GCH/4),dim3(256),0,stream>>>(nb0, itt, TW1, Ts1, Tt1,
        nullptr,nullptr,nullptr,nullptr,nullptr, H1hi, H1lo);
    k_mgemm<3,false><<<dim3(1,GCH*10/64),dim3(256),0,stream>>>(H1hi, H1lo, g1wT, g1wT+65536,
        nullptr,nullptr, g1as + CD, g1ad + CD, Zbuf, nullptr,nullptr, Zs, Zt, GCH*10, 256, 256);
    k_gatw2<10,true,true><<<dim3(GCH/4),dim3(256),0,stream>>>(nb0, itt, nullptr, nullptr,
        Zbuf, Zs, Zt, g1o, g1hi, g1lo, G1rs);
  }
  // GW = g1 @ g2W[0] (bf16x3 MFMA) with fused Gs/Gt row dots
  k_mgemm<3,false><<<dim3(1,NN/64),dim3(256),0,stream>>>(g1hi, g1lo, g2w0T, g2w0T+65536,
      nullptr,nullptr, g2as, g2ad, G1W, nullptr,nullptr, G1s, G1t, NN, 256, 256);
  for (int c=0;c<NN/GCH;c++){
    int nb0 = c*GCH;
    k_gatw1<15><<<dim3(GCH/4),dim3(256),0,stream>>>(nb0, itt, TW2, Ts2, Tt2,
        G1W, G1s, G1t, G1rs, l2m, H1hi, H1lo);
    k_mgemm<3,false><<<dim3(1,GCH*15/64),dim3(256),0,stream>>>(H1hi, H1lo, g2wT, g2wT+65536,
        nullptr,nullptr, g2as + CD, g2ad + CD, Zbuf, nullptr,nullptr, Zs, Zt, GCH*15, 256, 256);
    k_gatw2<15,false,false><<<dim3(GCH/4),dim3(256),0,stream>>>(nb0, itt, G1rs, l2m,
        Zbuf, Zs, Zt, g2o, nullptr, nullptr, nullptr);
  }
  k_x0<<<dim3(NSR),dim3(256),0,stream>>>(input_ids, mask_pos, mask_type, emb, g2o,
      ln1g, ln1b, xb, xhi, xlo);

  // ---- encoder (12 layers) ----
  for (int l=0;l<CL;l++){
    const ushort* qh = wqkvT + (size_t)l*2*768*256; const ushort* ql = qh + 768*256;
    const ushort* oh = woT   + (size_t)l*2*256*256; const ushort* ol = oh + 256*256;
    const ushort* ah = w1T   + (size_t)l*2*512*256; const ushort* a2 = ah + 512*256;
    const ushort* bh = w2T   + (size_t)l*2*256*512; const ushort* b2l= bh + 256*512;
    k_mgemm<0,false><<<dim3(3,NSR/64),dim3(256),0,stream>>>(xhi, xlo, qh, ql,
        nullptr,nullptr,nullptr,nullptr, qkvb, nullptr,nullptr, nullptr,nullptr, NSR, 768, 256);
    k_attn<<<dim3(CB*CH),dim3(128),0,stream>>>(qkvb, edge_labels, ektab, evtab, input_mask,
        ctxhi, ctxlo);
    k_mgemm<2,false><<<dim3(1,NSR/64),dim3(256),0,stream>>>(ctxhi, ctxlo, oh, ol,
        nullptr, xb, el1g + (size_t)l*CD, el1b + (size_t)l*CD, xb, xhi, xlo, nullptr,nullptr, NSR, 256, 256);
    k_mgemm<1,true><<<dim3(2,NSR/64),dim3(256),0,stream>>>(xhi, xlo, ah, a2,
        b1 + (size_t)l*512, nullptr,nullptr,nullptr, nullptr, ffhi, fflo, nullptr,nullptr, NSR, 512, 256);
    k_mgemm<2,true><<<dim3(1,NSR/64),dim3(256),0,stream>>>(ffhi, fflo, bh, b2l,
        b2 + (size_t)l*CD, xb, el2g + (size_t)l*CD, el2b + (size_t)l*CD, xb, xhi, xlo, nullptr,nullptr, NSR, 256, 512);
  }

  // ---- head / classifier / loss ----
  k_head<<<dim3(CB),dim3(256),0,stream>>>(xb, mask_pos, ln2g, ln2b, hm);
  k_fc<<<dim3((CNCLS+63)/64, CB/32),dim3(256),0,stream>>>(hm, emb, fc2b, fc3b, fcp);
  k_ce<<<dim3(CB),dim3(256),0,stream>>>(fcp, gtruth, mask_type, cer, cet);
  k_loss<<<dim3(1),dim3(256),0,stream>>>(cer, cet, mask_type, dout);
}